// Round 14
// baseline (786.391 us; speedup 1.0000x reference)
//
#include <hip/hip_runtime.h>
#include <stdint.h>

typedef __bf16 bf16;
typedef __bf16 bf16x4 __attribute__((ext_vector_type(4)));
typedef __bf16 bf16x8 __attribute__((ext_vector_type(8)));
typedef float f32x4 __attribute__((ext_vector_type(4)));

#define MFMA16(a, b, c) __builtin_amdgcn_mfma_f32_16x16x32_bf16((a), (b), (c), 0, 0, 0)

static constexpr int NB = 4;      // batch
static constexpr int NH = 16;     // heads
static constexpr int SL = 2048;   // seq len
static constexpr int HD = 64;     // head dim
static constexpr int ED = 1024;   // embed
static constexpr int MR = NB * SL; // 8192 rows

__device__ __forceinline__ void gl_lds16(const void* g, void* l) {
    __builtin_amdgcn_global_load_lds(
        (const __attribute__((address_space(1))) unsigned int*)g,
        (__attribute__((address_space(3))) unsigned int*)l, 16, 0, 0);
}

// ------------------- f32 -> bf16 hi/lo split -------------------
__global__ void k_split(const float* __restrict__ src, bf16* __restrict__ hi,
                        bf16* __restrict__ lo, int n4) {
    int i = blockIdx.x * blockDim.x + threadIdx.x;
    if (i >= n4) return;
    const float4 v = ((const float4*)src)[i];
    float vv[4] = {v.x, v.y, v.z, v.w};
    bf16x4 hv, lv;
#pragma unroll
    for (int e = 0; e < 4; ++e) {
        bf16 h = (bf16)vv[e];
        hv[e] = h;
        lv[e] = (bf16)(vv[e] - (float)h);
    }
    ((bf16x4*)hi)[i] = hv;
    ((bf16x4*)lo)[i] = lv;
}

// ------------------- QKV projection GEMM (hi/lo inputs, bf16 outputs) -------------------
__global__ __launch_bounds__(256) void k_qkv_gemm(
    const bf16* __restrict__ xh, const bf16* __restrict__ xl,
    const bf16* __restrict__ wh, const bf16* __restrict__ wl,
    const float* __restrict__ bq, const float* __restrict__ bk,
    const float* __restrict__ bv,
    bf16* __restrict__ qh, bf16* __restrict__ kh, bf16* __restrict__ vh)
{
    __shared__ __attribute__((aligned(16))) bf16 As[2][128 * 32];
    __shared__ __attribute__((aligned(16))) bf16 Bs[2][128 * 32];

    const int z  = blockIdx.z;           // 0=q,1=k,2=v
    const int m0 = blockIdx.x * 128;
    const int n0 = blockIdx.y * 128;
    const int tid = threadIdx.x, wave = tid >> 6, lane = tid & 63;
    const int wr = wave >> 1, wc = wave & 1;
    const int fr = lane & 15, fq = lane >> 4;
    const bf16* Wh = wh + (size_t)z * ED * ED;
    const bf16* Wl = wl + (size_t)z * ED * ED;

    const f32x4 z4 = {0.f, 0.f, 0.f, 0.f};
    f32x4 acc[4][4];
#pragma unroll
    for (int i = 0; i < 4; ++i)
#pragma unroll
        for (int j = 0; j < 4; ++j) acc[i][j] = z4;

#pragma unroll 1
    for (int kk = 0; kk < ED; kk += 32) {
#pragma unroll
        for (int r = 0; r < 2; ++r) {
            const int chunk = r * 256 + tid;
            const int row = chunk >> 2, c8 = (chunk & 3) * 8;
            const size_t ax = (size_t)(m0 + row) * ED + kk + c8;
            const size_t bx = (size_t)(n0 + row) * ED + kk + c8;
            const int db = (r * 256 + wave * 64) * 8;   // wave-uniform LDS base
            gl_lds16(xh + ax, &As[0][db]);
            gl_lds16(xl + ax, &As[1][db]);
            gl_lds16(Wh + bx, &Bs[0][db]);
            gl_lds16(Wl + bx, &Bs[1][db]);
        }
        __syncthreads();
        bf16x8 af[4][2], bfg[4][2];
#pragma unroll
        for (int i = 0; i < 4; ++i) {
            const int arow = wr * 64 + i * 16 + fr;
            af[i][0] = *(const bf16x8*)&As[0][arow * 32 + fq * 8];
            af[i][1] = *(const bf16x8*)&As[1][arow * 32 + fq * 8];
            const int brow = wc * 64 + i * 16 + fr;
            bfg[i][0] = *(const bf16x8*)&Bs[0][brow * 32 + fq * 8];
            bfg[i][1] = *(const bf16x8*)&Bs[1][brow * 32 + fq * 8];
        }
#pragma unroll
        for (int mi = 0; mi < 4; ++mi)
#pragma unroll
            for (int ni = 0; ni < 4; ++ni) {
                acc[mi][ni] = MFMA16(af[mi][0], bfg[ni][0], acc[mi][ni]);
                acc[mi][ni] = MFMA16(af[mi][0], bfg[ni][1], acc[mi][ni]);
                acc[mi][ni] = MFMA16(af[mi][1], bfg[ni][0], acc[mi][ni]);
            }
        __syncthreads();
    }

    const float* bias = (z == 0) ? bq : (z == 1) ? bk : bv;
#pragma unroll
    for (int mi = 0; mi < 4; ++mi) {
#pragma unroll
        for (int ni = 0; ni < 4; ++ni) {
            const int col = n0 + wc * 64 + ni * 16 + fr;
            const int hh = col >> 6, dd = col & 63;
#pragma unroll
            for (int j = 0; j < 4; ++j) {
                const int row = m0 + wr * 64 + mi * 16 + fq * 4 + j;
                float v = acc[mi][ni][j] + bias[col];
                const int nb = row >> 11, li = row & (SL - 1);
                const size_t off = (((size_t)nb * NH + hh) * SL + li) * HD + dd;
                if (z == 0) {
                    qh[off] = (bf16)(v * 0.125f);      // head_dim^-0.5
                } else if (z == 1) {
                    kh[off] = (bf16)v;
                } else {
                    vh[off] = (bf16)v;
                }
            }
        }
    }
}

// ------------------- output projection GEMM (hi/lo) -------------------
__global__ __launch_bounds__(256) void k_out_gemm(
    const bf16* __restrict__ ah, const bf16* __restrict__ al,
    const bf16* __restrict__ wh, const bf16* __restrict__ wl,
    const float* __restrict__ bo, float* __restrict__ out)
{
    __shared__ __attribute__((aligned(16))) bf16 As[2][128 * 32];
    __shared__ __attribute__((aligned(16))) bf16 Bs[2][128 * 32];

    const int m0 = blockIdx.x * 128;
    const int n0 = blockIdx.y * 128;
    const int tid = threadIdx.x, wave = tid >> 6, lane = tid & 63;
    const int wr = wave >> 1, wc = wave & 1;
    const int fr = lane & 15, fq = lane >> 4;

    const f32x4 z4 = {0.f, 0.f, 0.f, 0.f};
    f32x4 acc[4][4];
#pragma unroll
    for (int i = 0; i < 4; ++i)
#pragma unroll
        for (int j = 0; j < 4; ++j) acc[i][j] = z4;

#pragma unroll 1
    for (int kk = 0; kk < ED; kk += 32) {
#pragma unroll
        for (int r = 0; r < 2; ++r) {
            const int chunk = r * 256 + tid;
            const int row = chunk >> 2, c8 = (chunk & 3) * 8;
            const size_t ax = (size_t)(m0 + row) * ED + kk + c8;
            const size_t bx = (size_t)(n0 + row) * ED + kk + c8;
            const int db = (r * 256 + wave * 64) * 8;
            gl_lds16(ah + ax, &As[0][db]);
            gl_lds16(al + ax, &As[1][db]);
            gl_lds16(wh + bx, &Bs[0][db]);
            gl_lds16(wl + bx, &Bs[1][db]);
        }
        __syncthreads();
        bf16x8 af[4][2], bfg[4][2];
#pragma unroll
        for (int i = 0; i < 4; ++i) {
            const int arow = wr * 64 + i * 16 + fr;
            af[i][0] = *(const bf16x8*)&As[0][arow * 32 + fq * 8];
            af[i][1] = *(const bf16x8*)&As[1][arow * 32 + fq * 8];
            const int brow = wc * 64 + i * 16 + fr;
            bfg[i][0] = *(const bf16x8*)&Bs[0][brow * 32 + fq * 8];
            bfg[i][1] = *(const bf16x8*)&Bs[1][brow * 32 + fq * 8];
        }
#pragma unroll
        for (int mi = 0; mi < 4; ++mi)
#pragma unroll
            for (int ni = 0; ni < 4; ++ni) {
                acc[mi][ni] = MFMA16(af[mi][0], bfg[ni][0], acc[mi][ni]);
                acc[mi][ni] = MFMA16(af[mi][0], bfg[ni][1], acc[mi][ni]);
                acc[mi][ni] = MFMA16(af[mi][1], bfg[ni][0], acc[mi][ni]);
            }
        __syncthreads();
    }

#pragma unroll
    for (int mi = 0; mi < 4; ++mi)
#pragma unroll
        for (int ni = 0; ni < 4; ++ni) {
            const int col = n0 + wc * 64 + ni * 16 + fr;
#pragma unroll
            for (int j = 0; j < 4; ++j) {
                const int row = m0 + wr * 64 + mi * 16 + fq * 4 + j;
                out[(size_t)row * ED + col] = acc[mi][ni][j] + bo[col];
            }
        }
}

// ------------------- flash attention v8: bias issue-early/consume-late -------------------
// Bias for tile kt loaded FIRST in the iteration (before Vs writes / K DMA / V
// prefetch) so the softmax's waitcnt drains only bias, covered by staging+QK^T.
__global__ __launch_bounds__(256) void k_flash(
    const bf16* __restrict__ qh, const bf16* __restrict__ kh,
    const bf16* __restrict__ vh,
    const float* __restrict__ bias, const int* __restrict__ mask,
    bf16* __restrict__ ch, bf16* __restrict__ cl,
    float* __restrict__ mrow, float* __restrict__ srow)
{
    __shared__ __attribute__((aligned(16))) bf16 Ks[2][64 * 64];  // [key][d] swz, dbuf
    __shared__ __attribute__((aligned(16))) bf16 Vs[2][64 * 64];  // [d][key] swz, dbuf
    __shared__ __attribute__((aligned(16))) bf16 Ws[4][16 * 64];  // per-wave P, swz

    const int bid = blockIdx.x;
    const int xcd = bid & 7, local = bid >> 3;
    const int h = xcd * 2 + (local >> 6);
    const int rem = local & 63;
    const int qt = rem >> 2, n = rem & 3;

    const int tid = threadIdx.x, wave = tid >> 6, lane = tid & 63;
    const int fr = lane & 15, fq = lane >> 4;
    const int frx = fr & 7;
    const int q0 = qt * 128;
    const int qw = q0 + wave * 32;                  // wave's 32-row base
    const size_t hoff = ((size_t)n * NH + h) * SL * HD;
    const f32x4 z4 = {0.f, 0.f, 0.f, 0.f};

    bf16x8 qf0[2], qf1[2];
#pragma unroll
    for (int m = 0; m < 2; ++m) {
        const size_t qb = hoff + (size_t)(qw + m * 16 + fr) * HD + fq * 8;
        qf0[m] = *(const bf16x8*)(qh + qb);
        qf1[m] = *(const bf16x8*)(qh + qb + 32);
    }

    f32x4 o[2][4];
#pragma unroll
    for (int m = 0; m < 2; ++m)
#pragma unroll
        for (int f = 0; f < 4; ++f) o[m][f] = z4;
    float mj[2][4], sj[2][4];   // sj: LANE-LOCAL partial sums
#pragma unroll
    for (int m = 0; m < 2; ++m)
#pragma unroll
        for (int j = 0; j < 4; ++j) { mj[m][j] = -3e38f; sj[m][j] = 0.f; }

    const int* mkb = mask + n * SL;
    const float* bh = bias + (size_t)h * SL * SL;

    // ---- prologue ----
#pragma unroll
    for (int i = 0; i < 2; ++i) {
        const int li = i * 256 + tid;
        const int r = li >> 3, s = li & 7;
        gl_lds16(kh + hoff + (size_t)r * HD + (s ^ (r & 7)) * 8,
                 &Ks[0][(i * 256 + wave * 64) * 8]);
    }
    bf16x8 vr0 = *(const bf16x8*)(vh + hoff + (size_t)lane * HD + wave * 8);
    bf16x8 vr1 = *(const bf16x8*)(vh + hoff + (size_t)lane * HD + (wave + 4) * 8);
#pragma unroll
    for (int e = 0; e < 8; ++e) {
        const int d0 = wave * 8 + e, d1 = (wave + 4) * 8 + e;
        Vs[0][d0 * 64 + (((lane >> 3) ^ (d0 & 7)) << 3) + (lane & 7)] = vr0[e];
        Vs[0][d1 * 64 + (((lane >> 3) ^ (d1 & 7)) << 3) + (lane & 7)] = vr1[e];
    }
    vr0 = *(const bf16x8*)(vh + hoff + (size_t)(64 + lane) * HD + wave * 8);
    vr1 = *(const bf16x8*)(vh + hoff + (size_t)(64 + lane) * HD + (wave + 4) * 8);
    int mkc[4];
#pragma unroll
    for (int nf = 0; nf < 4; ++nf) mkc[nf] = mkb[nf * 16 + fr];
    __syncthreads();   // drains K(0) DMA + Vs[0] writes

#pragma unroll 1
    for (int kt = 0; kt < 32; ++kt) {
        const int cur = kt & 1, nxt = cur ^ 1;
        const int kp1 = (kt < 31) ? kt + 1 : 31;
        const int kp2 = (kt < 30) ? kt + 2 : 31;

        // 0. bias for THIS tile, issued first (oldest vmem -> waitcnt drains only these)
        float bfr[2][4][4];
#pragma unroll
        for (int m = 0; m < 2; ++m)
#pragma unroll
            for (int nf = 0; nf < 4; ++nf)
#pragma unroll
                for (int j = 0; j < 4; ++j)
                    bfr[m][nf][j] = bh[(size_t)(qw + m * 16 + fq * 4 + j) * SL
                                       + kt * 64 + nf * 16 + fr];

        // 1. Vs[nxt] <- vr (V(kt+1))
#pragma unroll
        for (int e = 0; e < 8; ++e) {
            const int d0 = wave * 8 + e, d1 = (wave + 4) * 8 + e;
            Vs[nxt][d0 * 64 + (((lane >> 3) ^ (d0 & 7)) << 3) + (lane & 7)] = vr0[e];
            Vs[nxt][d1 * 64 + (((lane >> 3) ^ (d1 & 7)) << 3) + (lane & 7)] = vr1[e];
        }
        // 2. issue K(kt+1) -> Ks[nxt]
#pragma unroll
        for (int i = 0; i < 2; ++i) {
            const int li = i * 256 + tid;
            const int r = li >> 3, s = li & 7;
            gl_lds16(kh + hoff + (size_t)(kp1 * 64 + r) * HD + (s ^ (r & 7)) * 8,
                     &Ks[nxt][(i * 256 + wave * 64) * 8]);
        }
        // 3. V(kt+2) -> regs
        vr0 = *(const bf16x8*)(vh + hoff + (size_t)(kp2 * 64 + lane) * HD + wave * 8);
        vr1 = *(const bf16x8*)(vh + hoff + (size_t)(kp2 * 64 + lane) * HD + (wave + 4) * 8);
        int mkn[4];
#pragma unroll
        for (int nf = 0; nf < 4; ++nf) mkn[nf] = mkb[kp1 * 64 + nf * 16 + fr];

        // ---- compute: two independent 16-row chains ----
#pragma unroll
        for (int m = 0; m < 2; ++m) {
            f32x4 sf[4];
            __builtin_amdgcn_s_setprio(1);
#pragma unroll
            for (int nf = 0; nf < 4; ++nf) {
                const bf16* kp = &Ks[cur][(nf * 16 + fr) * 64];
                const bf16x8 b0 = *(const bf16x8*)&kp[(fq ^ frx) * 8];
                const bf16x8 b1 = *(const bf16x8*)&kp[((fq + 4) ^ frx) * 8];
                f32x4 a = z4;
                a = MFMA16(qf0[m], b0, a);
                a = MFMA16(qf1[m], b1, a);
                sf[nf] = a;
            }
            __builtin_amdgcn_s_setprio(0);

            // bias + mask (bfr issued at iteration top)
#pragma unroll
            for (int nf = 0; nf < 4; ++nf) {
                const bool mk = mkc[nf] != 0;
#pragma unroll
                for (int j = 0; j < 4; ++j) {
                    float s = sf[nf][j] + bfr[m][nf][j];
                    sf[nf][j] = mk ? -1e30f : s;
                }
            }

            // defer-max online softmax (common path: no cross-lane ops)
            float tmax[4];
#pragma unroll
            for (int j = 0; j < 4; ++j)
                tmax[j] = fmaxf(fmaxf(sf[0][j], sf[1][j]), fmaxf(sf[2][j], sf[3][j]));
            bool need = false;
#pragma unroll
            for (int j = 0; j < 4; ++j)
                need = need || (tmax[j] > mj[m][j] + 8.0f);
            if (__any(need)) {
#pragma unroll
                for (int d = 1; d < 16; d <<= 1)
#pragma unroll
                    for (int j = 0; j < 4; ++j)
                        tmax[j] = fmaxf(tmax[j], __shfl_xor(tmax[j], d));
#pragma unroll
                for (int j = 0; j < 4; ++j) {
                    const float mn = fmaxf(mj[m][j], tmax[j]);
                    const float scale = __expf(mj[m][j] - mn);
                    mj[m][j] = mn;
                    sj[m][j] *= scale;
#pragma unroll
                    for (int f = 0; f < 4; ++f) o[m][f][j] *= scale;
                }
            }
#pragma unroll
            for (int nf = 0; nf < 4; ++nf)
#pragma unroll
                for (int j = 0; j < 4; ++j) {
                    const float w = __expf(sf[nf][j] - mj[m][j]);
                    sf[nf][j] = w;
                    sj[m][j] += w;
                }

            // P -> per-wave swizzled LDS tile (wave-local; reused across m)
#pragma unroll
            for (int nf = 0; nf < 4; ++nf)
#pragma unroll
                for (int j = 0; j < 4; ++j) {
                    const int row = fq * 4 + j, col = nf * 16 + fr;
                    Ws[wave][row * 64 + (((col >> 3) ^ (row & 7)) << 3) + (fr & 7)] =
                        (bf16)sf[nf][j];
                }
            const bf16* wp = &Ws[wave][fr * 64];
            const bf16x8 wa0 = *(const bf16x8*)&wp[(fq ^ frx) * 8];
            const bf16x8 wa1 = *(const bf16x8*)&wp[((fq + 4) ^ frx) * 8];
            __builtin_amdgcn_s_setprio(1);
#pragma unroll
            for (int f = 0; f < 4; ++f) {
                const bf16* vp = &Vs[cur][(f * 16 + fr) * 64];
                const bf16x8 vb0 = *(const bf16x8*)&vp[(fq ^ frx) * 8];
                const bf16x8 vb1 = *(const bf16x8*)&vp[((fq + 4) ^ frx) * 8];
                o[m][f] = MFMA16(wa0, vb0, o[m][f]);
                o[m][f] = MFMA16(wa1, vb1, o[m][f]);
            }
            __builtin_amdgcn_s_setprio(0);
        }

#pragma unroll
        for (int nf = 0; nf < 4; ++nf) mkc[nf] = mkn[nf];
        __syncthreads();   // drains K(kt+1) DMA; fences Ks/Vs buffer swap
    }

    // epilogue: reduce lane-local sj across the 16-lane row group (once)
#pragma unroll
    for (int m = 0; m < 2; ++m)
#pragma unroll
        for (int d = 1; d < 16; d <<= 1)
#pragma unroll
            for (int j = 0; j < 4; ++j)
                sj[m][j] += __shfl_xor(sj[m][j], d);

    // context (hi/lo) + row stats, both m
#pragma unroll
    for (int m = 0; m < 2; ++m) {
#pragma unroll
        for (int j = 0; j < 4; ++j) {
            const float inv = 1.0f / sj[m][j];
            const int row = n * SL + qw + m * 16 + fq * 4 + j;
#pragma unroll
            for (int f = 0; f < 4; ++f) {
                const float v = o[m][f][j] * inv;
                const size_t off = (size_t)row * ED + h * HD + f * 16 + fr;
                const bf16 hv = (bf16)v;
                ch[off] = hv;
                cl[off] = (bf16)(v - (float)hv);
            }
        }
        if (fr == 0) {
#pragma unroll
            for (int j = 0; j < 4; ++j) {
                const int r = qw + m * 16 + fq * 4 + j;
                mrow[((size_t)n * NH + h) * SL + r] = mj[m][j];
                srow[((size_t)n * NH + h) * SL + r] = sj[m][j];
            }
        }
    }
}

// ------------------- head-averaged weights v4: KT=64, inline exp-arg -------------------
// Block = (64 q-rows, 64 k-cols), all nn & h. 8 MFMA + 32 exp per barrier-step.
__global__ __launch_bounds__(256) void k_avg(
    const bf16* __restrict__ qh, const bf16* __restrict__ kh,
    const float* __restrict__ bias, const int* __restrict__ mask,
    const float* __restrict__ mrow, const float* __restrict__ srow,
    float* __restrict__ avg)
{
    __shared__ __attribute__((aligned(16))) bf16 Qs[2][64 * 64];  // 8KB x2
    __shared__ __attribute__((aligned(16))) bf16 Ks2[2][64 * 64]; // 8KB x2

    const int qt = blockIdx.x, kt = blockIdx.y;
    const int tid = threadIdx.x, wave = tid >> 6, lane = tid & 63;
    const int fr = lane & 15, fq = lane >> 4;
    const int frx = fr & 7;
    const int q0 = qt * 64, k0 = kt * 64;
    const int qr = q0 + wave * 16;
    const f32x4 z4 = {0.f, 0.f, 0.f, 0.f};

    f32x4 acc[4][4];   // [nn][nf] -- all compile-time indices
#pragma unroll
    for (int nn = 0; nn < 4; ++nn)
#pragma unroll
        for (int nf = 0; nf < 4; ++nf) acc[nn][nf] = z4;

    bool mk[4][4];
#pragma unroll
    for (int nn = 0; nn < 4; ++nn)
#pragma unroll
        for (int nf = 0; nf < 4; ++nf)
            mk[nn][nf] = mask[nn * SL + k0 + nf * 16 + fr] != 0;

    auto stage = [&](int hh, int nn2, int b) {
        const bf16* qb = qh + (((size_t)nn2 * NH + hh) * SL + q0) * HD;
        const bf16* kb = kh + (((size_t)nn2 * NH + hh) * SL + k0) * HD;
#pragma unroll
        for (int i = 0; i < 2; ++i) {
            const int li = i * 256 + tid;
            const int r = li >> 3, s = li & 7;
            gl_lds16(qb + (size_t)r * HD + (s ^ (r & 7)) * 8,
                     &Qs[b][(i * 256 + wave * 64) * 8]);
            gl_lds16(kb + (size_t)r * HD + (s ^ (r & 7)) * 8,
                     &Ks2[b][(i * 256 + wave * 64) * 8]);
        }
    };

    stage(0, 0, 0);
    __syncthreads();

    int cur = 0;
#pragma unroll 1
    for (int h = 0; h < NH; ++h) {
        float bfr[4][4];
#pragma unroll
        for (int nf = 0; nf < 4; ++nf)
#pragma unroll
            for (int j = 0; j < 4; ++j)
                bfr[nf][j] = bias[((size_t)h * SL + qr + fq * 4 + j) * SL + k0 + nf * 16 + fr];

#pragma unroll
        for (int nn = 0; nn < 4; ++nn) {
            const int ih = h * 4 + nn;
            const int nxt = cur ^ 1;
            if (ih < 63) stage((ih + 1) >> 2, (ih + 1) & 3, nxt);

            const size_t sidx = ((size_t)nn * NH + h) * SL + qr + fq * 4;
            const f32x4 mv = *(const f32x4*)(mrow + sidx);
            const f32x4 sv = *(const f32x4*)(srow + sidx);
            float mlg[4];
#pragma unroll
            for (int j = 0; j < 4; ++j)
                mlg[j] = mv[j] + __logf(16.0f * sv[j]);

            const bf16* qp = &Qs[cur][(wave * 16 + fr) * 64];
            const bf16x8 qf0 = *(const bf16x8*)&qp[(fq ^ frx) * 8];
            const bf16x8 qf1 = *(const bf16x8*)&qp[((fq + 4) ^ frx) * 8];
#pragma unroll
            for (int nf = 0; nf < 4; ++nf) {
                const bf16* kp = &Ks2[cur][(nf * 16 + fr) * 64];
                const bf16x8 b0 = *(const bf16x8*)&kp[(fq ^ frx) * 8];
                const bf16x8 b1 = *(const bf16x8*)&kp[((fq + 4) ^ frx) * 8];
                f32x4 a = z4;
                a = MFMA16(qf0, b0, a);
                a = MFMA16(qf1, b1, a);
#pragma unroll
                for (int j = 0; j < 4; ++j) {
                    const float w = mk[nn][nf] ? 0.f
                        : __expf(a[j] + bfr[nf][j] - mlg[j]);
                    acc[nn][nf][j] += w;
                }
            }
            __syncthreads();
            cur = nxt;
        }
    }

#pragma unroll
    for (int nn = 0; nn < 4; ++nn)
#pragma unroll
        for (int j = 0; j < 4; ++j) {
            const size_t rowoff = ((size_t)nn * SL + qr + fq * 4 + j) * SL;
#pragma unroll
            for (int nf = 0; nf < 4; ++nf)
                avg[rowoff + k0 + nf * 16 + fr] = acc[nn][nf][j];
        }
}

// ------------------- launcher -------------------
extern "C" void kernel_launch(void* const* d_in, const int* in_sizes, int n_in,
                              void* d_out, int out_size, void* d_ws, size_t ws_size,
                              hipStream_t stream)
{
    (void)in_sizes; (void)n_in; (void)out_size; (void)ws_size;
    const float* query = (const float*)d_in[0];
    const float* bias  = (const float*)d_in[1];
    const int* mask = (const int*)d_in[2];
    const float* Wq = (const float*)d_in[3];
    const float* bq = (const float*)d_in[4];
    const float* Wk = (const float*)d_in[5];
    const float* bk = (const float*)d_in[6];
    const float* Wv = (const float*)d_in[7];
    const float* bv = (const float*)d_in[8];
    const float* Wo = (const float*)d_in[9];
    const float* bo = (const float*)d_in[10];
    float* out0 = (float*)d_out;                      // [N,L,E]
    float* out1 = out0 + (size_t)MR * ED;             // [N,L,L]

    char* p = (char*)d_ws;
    auto carve = [&](size_t bytes) {
        char* r = p;
        p += (bytes + 255) & ~(size_t)255;
        return r;
    };
    const size_t QKVB = (size_t)NB * NH * SL * HD * 2;   // 16.78 MB
    bf16* xh = (bf16*)carve((size_t)MR * ED * 2);
    bf16* xl = (bf16*)carve((size_t)MR * ED * 2);
    bf16* wh = (bf16*)carve((size_t)4 * ED * ED * 2);
    bf16* wl = (bf16*)carve((size_t)4 * ED * ED * 2);
    bf16* qh = (bf16*)carve(QKVB);
    bf16* kh = (bf16*)carve(QKVB);
    bf16* vh = (bf16*)carve(QKVB);
    float* mrow = (float*)carve((size_t)NB * NH * SL * 4);
    float* srow = (float*)carve((size_t)NB * NH * SL * 4);
    bf16* ch = (bf16*)carve((size_t)MR * ED * 2);
    bf16* cl = (bf16*)carve((size_t)MR * ED * 2);

    // 1. split inputs to hi/lo bf16
    {
        const int n4 = MR * ED / 4;
        k_split<<<(n4 + 255) / 256, 256, 0, stream>>>(query, xh, xl, n4);
        const int w4 = ED * ED / 4;
        const float* Ws4[4] = {Wq, Wk, Wv, Wo};
        for (int i = 0; i < 4; ++i)
            k_split<<<(w4 + 255) / 256, 256, 0, stream>>>(
                Ws4[i], wh + (size_t)i * ED * ED, wl + (size_t)i * ED * ED, w4);
    }
    // 2. QKV projections
    k_qkv_gemm<<<dim3(MR / 128, ED / 128, 3), 256, 0, stream>>>(
        xh, xl, wh, wl, bq, bk, bv, qh, kh, vh);
    // 3. flash attention + row stats + context (QBLK=128 -> 1024 blocks)
    k_flash<<<dim3(1024), 256, 0, stream>>>(
        qh, kh, vh, bias, mask, ch, cl, mrow, srow);
    // 4. head-averaged attention weights (64x64 tiles)
    k_avg<<<dim3(SL / 64, SL / 64), 256, 0, stream>>>(
        qh, kh, bias, mask, mrow, srow, out1);
    // 5. output projection
    k_out_gemm<<<dim3(MR / 128, ED / 128), 256, 0, stream>>>(
        ch, cl, wh + (size_t)3 * ED * ED, wl + (size_t)3 * ED * ED, bo, out0);
}

// Round 15
// 637.360 us; speedup vs baseline: 1.2338x; 1.2338x over previous
//
#include <hip/hip_runtime.h>
#include <stdint.h>

typedef __bf16 bf16;
typedef __bf16 bf16x4 __attribute__((ext_vector_type(4)));
typedef __bf16 bf16x8 __attribute__((ext_vector_type(8)));
typedef float f32x4 __attribute__((ext_vector_type(4)));

#define MFMA16(a, b, c) __builtin_amdgcn_mfma_f32_16x16x32_bf16((a), (b), (c), 0, 0, 0)

static constexpr int NB = 4;      // batch
static constexpr int NH = 16;     // heads
static constexpr int SL = 2048;   // seq len
static constexpr int HD = 64;     // head dim
static constexpr int ED = 1024;   // embed
static constexpr int MR = NB * SL; // 8192 rows

__device__ __forceinline__ void gl_lds16(const void* g, void* l) {
    __builtin_amdgcn_global_load_lds(
        (const __attribute__((address_space(1))) unsigned int*)g,
        (__attribute__((address_space(3))) unsigned int*)l, 16, 0, 0);
}

// ------------------- f32 -> bf16 hi/lo split -------------------
__global__ void k_split(const float* __restrict__ src, bf16* __restrict__ hi,
                        bf16* __restrict__ lo, int n4) {
    int i = blockIdx.x * blockDim.x + threadIdx.x;
    if (i >= n4) return;
    const float4 v = ((const float4*)src)[i];
    float vv[4] = {v.x, v.y, v.z, v.w};
    bf16x4 hv, lv;
#pragma unroll
    for (int e = 0; e < 4; ++e) {
        bf16 h = (bf16)vv[e];
        hv[e] = h;
        lv[e] = (bf16)(vv[e] - (float)h);
    }
    ((bf16x4*)hi)[i] = hv;
    ((bf16x4*)lo)[i] = lv;
}

// ------------------- QKV projection GEMM (hi/lo inputs, bf16 outputs) -------------------
__global__ __launch_bounds__(256) void k_qkv_gemm(
    const bf16* __restrict__ xh, const bf16* __restrict__ xl,
    const bf16* __restrict__ wh, const bf16* __restrict__ wl,
    const float* __restrict__ bq, const float* __restrict__ bk,
    const float* __restrict__ bv,
    bf16* __restrict__ qh, bf16* __restrict__ kh, bf16* __restrict__ vh)
{
    __shared__ __attribute__((aligned(16))) bf16 As[2][128 * 32];
    __shared__ __attribute__((aligned(16))) bf16 Bs[2][128 * 32];

    const int z  = blockIdx.z;           // 0=q,1=k,2=v
    const int m0 = blockIdx.x * 128;
    const int n0 = blockIdx.y * 128;
    const int tid = threadIdx.x, wave = tid >> 6, lane = tid & 63;
    const int wr = wave >> 1, wc = wave & 1;
    const int fr = lane & 15, fq = lane >> 4;
    const bf16* Wh = wh + (size_t)z * ED * ED;
    const bf16* Wl = wl + (size_t)z * ED * ED;

    const f32x4 z4 = {0.f, 0.f, 0.f, 0.f};
    f32x4 acc[4][4];
#pragma unroll
    for (int i = 0; i < 4; ++i)
#pragma unroll
        for (int j = 0; j < 4; ++j) acc[i][j] = z4;

#pragma unroll 1
    for (int kk = 0; kk < ED; kk += 32) {
#pragma unroll
        for (int r = 0; r < 2; ++r) {
            const int chunk = r * 256 + tid;
            const int row = chunk >> 2, c8 = (chunk & 3) * 8;
            const size_t ax = (size_t)(m0 + row) * ED + kk + c8;
            const size_t bx = (size_t)(n0 + row) * ED + kk + c8;
            const int db = (r * 256 + wave * 64) * 8;   // wave-uniform LDS base
            gl_lds16(xh + ax, &As[0][db]);
            gl_lds16(xl + ax, &As[1][db]);
            gl_lds16(Wh + bx, &Bs[0][db]);
            gl_lds16(Wl + bx, &Bs[1][db]);
        }
        __syncthreads();
        bf16x8 af[4][2], bfg[4][2];
#pragma unroll
        for (int i = 0; i < 4; ++i) {
            const int arow = wr * 64 + i * 16 + fr;
            af[i][0] = *(const bf16x8*)&As[0][arow * 32 + fq * 8];
            af[i][1] = *(const bf16x8*)&As[1][arow * 32 + fq * 8];
            const int brow = wc * 64 + i * 16 + fr;
            bfg[i][0] = *(const bf16x8*)&Bs[0][brow * 32 + fq * 8];
            bfg[i][1] = *(const bf16x8*)&Bs[1][brow * 32 + fq * 8];
        }
#pragma unroll
        for (int mi = 0; mi < 4; ++mi)
#pragma unroll
            for (int ni = 0; ni < 4; ++ni) {
                acc[mi][ni] = MFMA16(af[mi][0], bfg[ni][0], acc[mi][ni]);
                acc[mi][ni] = MFMA16(af[mi][0], bfg[ni][1], acc[mi][ni]);
                acc[mi][ni] = MFMA16(af[mi][1], bfg[ni][0], acc[mi][ni]);
            }
        __syncthreads();
    }

    const float* bias = (z == 0) ? bq : (z == 1) ? bk : bv;
#pragma unroll
    for (int mi = 0; mi < 4; ++mi) {
#pragma unroll
        for (int ni = 0; ni < 4; ++ni) {
            const int col = n0 + wc * 64 + ni * 16 + fr;
            const int hh = col >> 6, dd = col & 63;
#pragma unroll
            for (int j = 0; j < 4; ++j) {
                const int row = m0 + wr * 64 + mi * 16 + fq * 4 + j;
                float v = acc[mi][ni][j] + bias[col];
                const int nb = row >> 11, li = row & (SL - 1);
                const size_t off = (((size_t)nb * NH + hh) * SL + li) * HD + dd;
                if (z == 0) {
                    qh[off] = (bf16)(v * 0.125f);      // head_dim^-0.5
                } else if (z == 1) {
                    kh[off] = (bf16)v;
                } else {
                    vh[off] = (bf16)v;
                }
            }
        }
    }
}

// ------------------- output projection GEMM (hi/lo) -------------------
__global__ __launch_bounds__(256) void k_out_gemm(
    const bf16* __restrict__ ah, const bf16* __restrict__ al,
    const bf16* __restrict__ wh, const bf16* __restrict__ wl,
    const float* __restrict__ bo, float* __restrict__ out)
{
    __shared__ __attribute__((aligned(16))) bf16 As[2][128 * 32];
    __shared__ __attribute__((aligned(16))) bf16 Bs[2][128 * 32];

    const int m0 = blockIdx.x * 128;
    const int n0 = blockIdx.y * 128;
    const int tid = threadIdx.x, wave = tid >> 6, lane = tid & 63;
    const int wr = wave >> 1, wc = wave & 1;
    const int fr = lane & 15, fq = lane >> 4;

    const f32x4 z4 = {0.f, 0.f, 0.f, 0.f};
    f32x4 acc[4][4];
#pragma unroll
    for (int i = 0; i < 4; ++i)
#pragma unroll
        for (int j = 0; j < 4; ++j) acc[i][j] = z4;

#pragma unroll 1
    for (int kk = 0; kk < ED; kk += 32) {
#pragma unroll
        for (int r = 0; r < 2; ++r) {
            const int chunk = r * 256 + tid;
            const int row = chunk >> 2, c8 = (chunk & 3) * 8;
            const size_t ax = (size_t)(m0 + row) * ED + kk + c8;
            const size_t bx = (size_t)(n0 + row) * ED + kk + c8;
            const int db = (r * 256 + wave * 64) * 8;
            gl_lds16(ah + ax, &As[0][db]);
            gl_lds16(al + ax, &As[1][db]);
            gl_lds16(wh + bx, &Bs[0][db]);
            gl_lds16(wl + bx, &Bs[1][db]);
        }
        __syncthreads();
        bf16x8 af[4][2], bfg[4][2];
#pragma unroll
        for (int i = 0; i < 4; ++i) {
            const int arow = wr * 64 + i * 16 + fr;
            af[i][0] = *(const bf16x8*)&As[0][arow * 32 + fq * 8];
            af[i][1] = *(const bf16x8*)&As[1][arow * 32 + fq * 8];
            const int brow = wc * 64 + i * 16 + fr;
            bfg[i][0] = *(const bf16x8*)&Bs[0][brow * 32 + fq * 8];
            bfg[i][1] = *(const bf16x8*)&Bs[1][brow * 32 + fq * 8];
        }
#pragma unroll
        for (int mi = 0; mi < 4; ++mi)
#pragma unroll
            for (int ni = 0; ni < 4; ++ni) {
                acc[mi][ni] = MFMA16(af[mi][0], bfg[ni][0], acc[mi][ni]);
                acc[mi][ni] = MFMA16(af[mi][0], bfg[ni][1], acc[mi][ni]);
                acc[mi][ni] = MFMA16(af[mi][1], bfg[ni][0], acc[mi][ni]);
            }
        __syncthreads();
    }

#pragma unroll
    for (int mi = 0; mi < 4; ++mi)
#pragma unroll
        for (int ni = 0; ni < 4; ++ni) {
            const int col = n0 + wc * 64 + ni * 16 + fr;
#pragma unroll
            for (int j = 0; j < 4; ++j) {
                const int row = m0 + wr * 64 + mi * 16 + fq * 4 + j;
                out[(size_t)row * ED + col] = acc[mi][ni][j] + bo[col];
            }
        }
}

// ------------------- flash attention v7 (restored): QBLK=128 + defer-max + lazy sum -------------------
// Bias loaded per-m inside compute (16 transient floats): VGPR stays at 128,
// the occupancy-cliff boundary. Do NOT hoist more live state into the loop.
__global__ __launch_bounds__(256) void k_flash(
    const bf16* __restrict__ qh, const bf16* __restrict__ kh,
    const bf16* __restrict__ vh,
    const float* __restrict__ bias, const int* __restrict__ mask,
    bf16* __restrict__ ch, bf16* __restrict__ cl,
    float* __restrict__ mrow, float* __restrict__ srow)
{
    __shared__ __attribute__((aligned(16))) bf16 Ks[2][64 * 64];  // [key][d] swz, dbuf
    __shared__ __attribute__((aligned(16))) bf16 Vs[2][64 * 64];  // [d][key] swz, dbuf
    __shared__ __attribute__((aligned(16))) bf16 Ws[4][16 * 64];  // per-wave P, swz

    const int bid = blockIdx.x;
    const int xcd = bid & 7, local = bid >> 3;
    const int h = xcd * 2 + (local >> 6);
    const int rem = local & 63;
    const int qt = rem >> 2, n = rem & 3;

    const int tid = threadIdx.x, wave = tid >> 6, lane = tid & 63;
    const int fr = lane & 15, fq = lane >> 4;
    const int frx = fr & 7;
    const int q0 = qt * 128;
    const int qw = q0 + wave * 32;                  // wave's 32-row base
    const size_t hoff = ((size_t)n * NH + h) * SL * HD;
    const f32x4 z4 = {0.f, 0.f, 0.f, 0.f};

    bf16x8 qf0[2], qf1[2];
#pragma unroll
    for (int m = 0; m < 2; ++m) {
        const size_t qb = hoff + (size_t)(qw + m * 16 + fr) * HD + fq * 8;
        qf0[m] = *(const bf16x8*)(qh + qb);
        qf1[m] = *(const bf16x8*)(qh + qb + 32);
    }

    f32x4 o[2][4];
#pragma unroll
    for (int m = 0; m < 2; ++m)
#pragma unroll
        for (int f = 0; f < 4; ++f) o[m][f] = z4;
    float mj[2][4], sj[2][4];   // sj: LANE-LOCAL partial sums
#pragma unroll
    for (int m = 0; m < 2; ++m)
#pragma unroll
        for (int j = 0; j < 4; ++j) { mj[m][j] = -3e38f; sj[m][j] = 0.f; }

    const int* mkb = mask + n * SL;
    const float* bh = bias + (size_t)h * SL * SL;

    // ---- prologue ----
#pragma unroll
    for (int i = 0; i < 2; ++i) {
        const int li = i * 256 + tid;
        const int r = li >> 3, s = li & 7;
        gl_lds16(kh + hoff + (size_t)r * HD + (s ^ (r & 7)) * 8,
                 &Ks[0][(i * 256 + wave * 64) * 8]);
    }
    bf16x8 vr0 = *(const bf16x8*)(vh + hoff + (size_t)lane * HD + wave * 8);
    bf16x8 vr1 = *(const bf16x8*)(vh + hoff + (size_t)lane * HD + (wave + 4) * 8);
#pragma unroll
    for (int e = 0; e < 8; ++e) {
        const int d0 = wave * 8 + e, d1 = (wave + 4) * 8 + e;
        Vs[0][d0 * 64 + (((lane >> 3) ^ (d0 & 7)) << 3) + (lane & 7)] = vr0[e];
        Vs[0][d1 * 64 + (((lane >> 3) ^ (d1 & 7)) << 3) + (lane & 7)] = vr1[e];
    }
    vr0 = *(const bf16x8*)(vh + hoff + (size_t)(64 + lane) * HD + wave * 8);
    vr1 = *(const bf16x8*)(vh + hoff + (size_t)(64 + lane) * HD + (wave + 4) * 8);
    int mkc[4];
#pragma unroll
    for (int nf = 0; nf < 4; ++nf) mkc[nf] = mkb[nf * 16 + fr];
    __syncthreads();   // drains K(0) DMA + Vs[0] writes

#pragma unroll 1
    for (int kt = 0; kt < 32; ++kt) {
        const int cur = kt & 1, nxt = cur ^ 1;
        const int kp1 = (kt < 31) ? kt + 1 : 31;
        const int kp2 = (kt < 30) ? kt + 2 : 31;

        // Vs[nxt] <- vr (V(kt+1))
#pragma unroll
        for (int e = 0; e < 8; ++e) {
            const int d0 = wave * 8 + e, d1 = (wave + 4) * 8 + e;
            Vs[nxt][d0 * 64 + (((lane >> 3) ^ (d0 & 7)) << 3) + (lane & 7)] = vr0[e];
            Vs[nxt][d1 * 64 + (((lane >> 3) ^ (d1 & 7)) << 3) + (lane & 7)] = vr1[e];
        }
        // issue K(kt+1) -> Ks[nxt]
#pragma unroll
        for (int i = 0; i < 2; ++i) {
            const int li = i * 256 + tid;
            const int r = li >> 3, s = li & 7;
            gl_lds16(kh + hoff + (size_t)(kp1 * 64 + r) * HD + (s ^ (r & 7)) * 8,
                     &Ks[nxt][(i * 256 + wave * 64) * 8]);
        }
        // V(kt+2) -> regs
        vr0 = *(const bf16x8*)(vh + hoff + (size_t)(kp2 * 64 + lane) * HD + wave * 8);
        vr1 = *(const bf16x8*)(vh + hoff + (size_t)(kp2 * 64 + lane) * HD + (wave + 4) * 8);
        int mkn[4];
#pragma unroll
        for (int nf = 0; nf < 4; ++nf) mkn[nf] = mkb[kp1 * 64 + nf * 16 + fr];

        // ---- compute: two independent 16-row chains ----
#pragma unroll
        for (int m = 0; m < 2; ++m) {
            float bfr[4][4];
#pragma unroll
            for (int nf = 0; nf < 4; ++nf)
#pragma unroll
                for (int j = 0; j < 4; ++j)
                    bfr[nf][j] = bh[(size_t)(qw + m * 16 + fq * 4 + j) * SL
                                    + kt * 64 + nf * 16 + fr];

            f32x4 sf[4];
            __builtin_amdgcn_s_setprio(1);
#pragma unroll
            for (int nf = 0; nf < 4; ++nf) {
                const bf16* kp = &Ks[cur][(nf * 16 + fr) * 64];
                const bf16x8 b0 = *(const bf16x8*)&kp[(fq ^ frx) * 8];
                const bf16x8 b1 = *(const bf16x8*)&kp[((fq + 4) ^ frx) * 8];
                f32x4 a = z4;
                a = MFMA16(qf0[m], b0, a);
                a = MFMA16(qf1[m], b1, a);
                sf[nf] = a;
            }
            __builtin_amdgcn_s_setprio(0);

            // bias + mask
#pragma unroll
            for (int nf = 0; nf < 4; ++nf) {
                const bool mk = mkc[nf] != 0;
#pragma unroll
                for (int j = 0; j < 4; ++j) {
                    float s = sf[nf][j] + bfr[nf][j];
                    sf[nf][j] = mk ? -1e30f : s;
                }
            }

            // defer-max online softmax (common path: no cross-lane ops)
            float tmax[4];
#pragma unroll
            for (int j = 0; j < 4; ++j)
                tmax[j] = fmaxf(fmaxf(sf[0][j], sf[1][j]), fmaxf(sf[2][j], sf[3][j]));
            bool need = false;
#pragma unroll
            for (int j = 0; j < 4; ++j)
                need = need || (tmax[j] > mj[m][j] + 8.0f);
            if (__any(need)) {
#pragma unroll
                for (int d = 1; d < 16; d <<= 1)
#pragma unroll
                    for (int j = 0; j < 4; ++j)
                        tmax[j] = fmaxf(tmax[j], __shfl_xor(tmax[j], d));
#pragma unroll
                for (int j = 0; j < 4; ++j) {
                    const float mn = fmaxf(mj[m][j], tmax[j]);
                    const float scale = __expf(mj[m][j] - mn);
                    mj[m][j] = mn;
                    sj[m][j] *= scale;
#pragma unroll
                    for (int f = 0; f < 4; ++f) o[m][f][j] *= scale;
                }
            }
#pragma unroll
            for (int nf = 0; nf < 4; ++nf)
#pragma unroll
                for (int j = 0; j < 4; ++j) {
                    const float w = __expf(sf[nf][j] - mj[m][j]);
                    sf[nf][j] = w;
                    sj[m][j] += w;
                }

            // P -> per-wave swizzled LDS tile (wave-local; reused across m)
#pragma unroll
            for (int nf = 0; nf < 4; ++nf)
#pragma unroll
                for (int j = 0; j < 4; ++j) {
                    const int row = fq * 4 + j, col = nf * 16 + fr;
                    Ws[wave][row * 64 + (((col >> 3) ^ (row & 7)) << 3) + (fr & 7)] =
                        (bf16)sf[nf][j];
                }
            const bf16* wp = &Ws[wave][fr * 64];
            const bf16x8 wa0 = *(const bf16x8*)&wp[(fq ^ frx) * 8];
            const bf16x8 wa1 = *(const bf16x8*)&wp[((fq + 4) ^ frx) * 8];
            __builtin_amdgcn_s_setprio(1);
#pragma unroll
            for (int f = 0; f < 4; ++f) {
                const bf16* vp = &Vs[cur][(f * 16 + fr) * 64];
                const bf16x8 vb0 = *(const bf16x8*)&vp[(fq ^ frx) * 8];
                const bf16x8 vb1 = *(const bf16x8*)&vp[((fq + 4) ^ frx) * 8];
                o[m][f] = MFMA16(wa0, vb0, o[m][f]);
                o[m][f] = MFMA16(wa1, vb1, o[m][f]);
            }
            __builtin_amdgcn_s_setprio(0);
        }

#pragma unroll
        for (int nf = 0; nf < 4; ++nf) mkc[nf] = mkn[nf];
        __syncthreads();   // drains K(kt+1) DMA; fences Ks/Vs buffer swap
    }

    // epilogue: reduce lane-local sj across the 16-lane row group (once)
#pragma unroll
    for (int m = 0; m < 2; ++m)
#pragma unroll
        for (int d = 1; d < 16; d <<= 1)
#pragma unroll
            for (int j = 0; j < 4; ++j)
                sj[m][j] += __shfl_xor(sj[m][j], d);

    // context (hi/lo) + row stats, both m
#pragma unroll
    for (int m = 0; m < 2; ++m) {
#pragma unroll
        for (int j = 0; j < 4; ++j) {
            const float inv = 1.0f / sj[m][j];
            const int row = n * SL + qw + m * 16 + fq * 4 + j;
#pragma unroll
            for (int f = 0; f < 4; ++f) {
                const float v = o[m][f][j] * inv;
                const size_t off = (size_t)row * ED + h * HD + f * 16 + fr;
                const bf16 hv = (bf16)v;
                ch[off] = hv;
                cl[off] = (bf16)(v - (float)hv);
            }
        }
        if (fr == 0) {
#pragma unroll
            for (int j = 0; j < 4; ++j) {
                const int r = qw + m * 16 + fq * 4 + j;
                mrow[((size_t)n * NH + h) * SL + r] = mj[m][j];
                srow[((size_t)n * NH + h) * SL + r] = sj[m][j];
            }
        }
    }
}

// ------------------- head-averaged weights v4: KT=64, inline exp-arg -------------------
__global__ __launch_bounds__(256) void k_avg(
    const bf16* __restrict__ qh, const bf16* __restrict__ kh,
    const float* __restrict__ bias, const int* __restrict__ mask,
    const float* __restrict__ mrow, const float* __restrict__ srow,
    float* __restrict__ avg)
{
    __shared__ __attribute__((aligned(16))) bf16 Qs[2][64 * 64];  // 8KB x2
    __shared__ __attribute__((aligned(16))) bf16 Ks2[2][64 * 64]; // 8KB x2

    const int qt = blockIdx.x, kt = blockIdx.y;
    const int tid = threadIdx.x, wave = tid >> 6, lane = tid & 63;
    const int fr = lane & 15, fq = lane >> 4;
    const int frx = fr & 7;
    const int q0 = qt * 64, k0 = kt * 64;
    const int qr = q0 + wave * 16;
    const f32x4 z4 = {0.f, 0.f, 0.f, 0.f};

    f32x4 acc[4][4];   // [nn][nf] -- all compile-time indices
#pragma unroll
    for (int nn = 0; nn < 4; ++nn)
#pragma unroll
        for (int nf = 0; nf < 4; ++nf) acc[nn][nf] = z4;

    bool mk[4][4];
#pragma unroll
    for (int nn = 0; nn < 4; ++nn)
#pragma unroll
        for (int nf = 0; nf < 4; ++nf)
            mk[nn][nf] = mask[nn * SL + k0 + nf * 16 + fr] != 0;

    auto stage = [&](int hh, int nn2, int b) {
        const bf16* qb = qh + (((size_t)nn2 * NH + hh) * SL + q0) * HD;
        const bf16* kb = kh + (((size_t)nn2 * NH + hh) * SL + k0) * HD;
#pragma unroll
        for (int i = 0; i < 2; ++i) {
            const int li = i * 256 + tid;
            const int r = li >> 3, s = li & 7;
            gl_lds16(qb + (size_t)r * HD + (s ^ (r & 7)) * 8,
                     &Qs[b][(i * 256 + wave * 64) * 8]);
            gl_lds16(kb + (size_t)r * HD + (s ^ (r & 7)) * 8,
                     &Ks2[b][(i * 256 + wave * 64) * 8]);
        }
    };

    stage(0, 0, 0);
    __syncthreads();

    int cur = 0;
#pragma unroll 1
    for (int h = 0; h < NH; ++h) {
        float bfr[4][4];
#pragma unroll
        for (int nf = 0; nf < 4; ++nf)
#pragma unroll
            for (int j = 0; j < 4; ++j)
                bfr[nf][j] = bias[((size_t)h * SL + qr + fq * 4 + j) * SL + k0 + nf * 16 + fr];

#pragma unroll
        for (int nn = 0; nn < 4; ++nn) {
            const int ih = h * 4 + nn;
            const int nxt = cur ^ 1;
            if (ih < 63) stage((ih + 1) >> 2, (ih + 1) & 3, nxt);

            const size_t sidx = ((size_t)nn * NH + h) * SL + qr + fq * 4;
            const f32x4 mv = *(const f32x4*)(mrow + sidx);
            const f32x4 sv = *(const f32x4*)(srow + sidx);
            float mlg[4];
#pragma unroll
            for (int j = 0; j < 4; ++j)
                mlg[j] = mv[j] + __logf(16.0f * sv[j]);

            const bf16* qp = &Qs[cur][(wave * 16 + fr) * 64];
            const bf16x8 qf0 = *(const bf16x8*)&qp[(fq ^ frx) * 8];
            const bf16x8 qf1 = *(const bf16x8*)&qp[((fq + 4) ^ frx) * 8];
#pragma unroll
            for (int nf = 0; nf < 4; ++nf) {
                const bf16* kp = &Ks2[cur][(nf * 16 + fr) * 64];
                const bf16x8 b0 = *(const bf16x8*)&kp[(fq ^ frx) * 8];
                const bf16x8 b1 = *(const bf16x8*)&kp[((fq + 4) ^ frx) * 8];
                f32x4 a = z4;
                a = MFMA16(qf0, b0, a);
                a = MFMA16(qf1, b1, a);
#pragma unroll
                for (int j = 0; j < 4; ++j) {
                    const float w = mk[nn][nf] ? 0.f
                        : __expf(a[j] + bfr[nf][j] - mlg[j]);
                    acc[nn][nf][j] += w;
                }
            }
            __syncthreads();
            cur = nxt;
        }
    }

#pragma unroll
    for (int nn = 0; nn < 4; ++nn)
#pragma unroll
        for (int j = 0; j < 4; ++j) {
            const size_t rowoff = ((size_t)nn * SL + qr + fq * 4 + j) * SL;
#pragma unroll
            for (int nf = 0; nf < 4; ++nf)
                avg[rowoff + k0 + nf * 16 + fr] = acc[nn][nf][j];
        }
}

// ------------------- launcher -------------------
extern "C" void kernel_launch(void* const* d_in, const int* in_sizes, int n_in,
                              void* d_out, int out_size, void* d_ws, size_t ws_size,
                              hipStream_t stream)
{
    (void)in_sizes; (void)n_in; (void)out_size; (void)ws_size;
    const float* query = (const float*)d_in[0];
    const float* bias  = (const float*)d_in[1];
    const int* mask = (const int*)d_in[2];
    const float* Wq = (const float*)d_in[3];
    const float* bq = (const float*)d_in[4];
    const float* Wk = (const float*)d_in[5];
    const float* bk = (const float*)d_in[6];
    const float* Wv = (const float*)d_in[7];
    const float* bv = (const float*)d_in[8];
    const float* Wo = (const float*)d_in[9];
    const float* bo = (const float*)d_in[10];
    float* out0 = (float*)d_out;                      // [N,L,E]
    float* out1 = out0 + (size_t)MR * ED;             // [N,L,L]

    char* p = (char*)d_ws;
    auto carve = [&](size_t bytes) {
        char* r = p;
        p += (bytes + 255) & ~(size_t)255;
        return r;
    };
    const size_t QKVB = (size_t)NB * NH * SL * HD * 2;   // 16.78 MB
    bf16* xh = (bf16*)carve((size_t)MR * ED * 2);
    bf16* xl = (bf16*)carve((size_t)MR * ED * 2);
    bf16* wh = (bf16*)carve((size_t)4 * ED * ED * 2);
    bf16* wl = (bf16*)carve((size_t)4 * ED * ED * 2);
    bf16* qh = (bf16*)carve(QKVB);
    bf16* kh = (bf16*)carve(QKVB);
    bf16* vh = (bf16*)carve(QKVB);
    float* mrow = (float*)carve((size_t)NB * NH * SL * 4);
    float* srow = (float*)carve((size_t)NB * NH * SL * 4);
    bf16* ch = (bf16*)carve((size_t)MR * ED * 2);
    bf16* cl = (bf16*)carve((size_t)MR * ED * 2);

    // 1. split inputs to hi/lo bf16
    {
        const int n4 = MR * ED / 4;
        k_split<<<(n4 + 255) / 256, 256, 0, stream>>>(query, xh, xl, n4);
        const int w4 = ED * ED / 4;
        const float* Ws4[4] = {Wq, Wk, Wv, Wo};
        for (int i = 0; i < 4; ++i)
            k_split<<<(w4 + 255) / 256, 256, 0, stream>>>(
                Ws4[i], wh + (size_t)i * ED * ED, wl + (size_t)i * ED * ED, w4);
    }
    // 2. QKV projections
    k_qkv_gemm<<<dim3(MR / 128, ED / 128, 3), 256, 0, stream>>>(
        xh, xl, wh, wl, bq, bk, bv, qh, kh, vh);
    // 3. flash attention + row stats + context (QBLK=128 -> 1024 blocks)
    k_flash<<<dim3(1024), 256, 0, stream>>>(
        qh, kh, vh, bias, mask, ch, cl, mrow, srow);
    // 4. head-averaged attention weights (64x64 tiles)
    k_avg<<<dim3(SL / 64, SL / 64), 256, 0, stream>>>(
        qh, kh, bias, mask, mrow, srow, out1);
    // 5. output projection
    k_out_gemm<<<dim3(MR / 128, ED / 128), 256, 0, stream>>>(
        ch, cl, wh + (size_t)3 * ED * ED, wl + (size_t)3 * ED * ED, bo, out0);
}

// Round 16
// 618.206 us; speedup vs baseline: 1.2721x; 1.0310x over previous
//
#include <hip/hip_runtime.h>
#include <stdint.h>

typedef __bf16 bf16;
typedef __bf16 bf16x4 __attribute__((ext_vector_type(4)));
typedef __bf16 bf16x8 __attribute__((ext_vector_type(8)));
typedef float f32x4 __attribute__((ext_vector_type(4)));

#define MFMA16(a, b, c) __builtin_amdgcn_mfma_f32_16x16x32_bf16((a), (b), (c), 0, 0, 0)

static constexpr int NB = 4;      // batch
static constexpr int NH = 16;     // heads
static constexpr int SL = 2048;   // seq len
static constexpr int HD = 64;     // head dim
static constexpr int ED = 1024;   // embed
static constexpr int MR = NB * SL; // 8192 rows

__device__ __forceinline__ void gl_lds16(const void* g, void* l) {
    __builtin_amdgcn_global_load_lds(
        (const __attribute__((address_space(1))) unsigned int*)g,
        (__attribute__((address_space(3))) unsigned int*)l, 16, 0, 0);
}

// ------------------- f32 -> bf16 hi/lo split -------------------
__global__ void k_split(const float* __restrict__ src, bf16* __restrict__ hi,
                        bf16* __restrict__ lo, int n4) {
    int i = blockIdx.x * blockDim.x + threadIdx.x;
    if (i >= n4) return;
    const float4 v = ((const float4*)src)[i];
    float vv[4] = {v.x, v.y, v.z, v.w};
    bf16x4 hv, lv;
#pragma unroll
    for (int e = 0; e < 4; ++e) {
        bf16 h = (bf16)vv[e];
        hv[e] = h;
        lv[e] = (bf16)(vv[e] - (float)h);
    }
    ((bf16x4*)hi)[i] = hv;
    ((bf16x4*)lo)[i] = lv;
}

// ------------------- mlg precompute: mlg = m + ln(16 s) -------------------
__global__ void k_mlg(const float* __restrict__ mrow, const float* __restrict__ srow,
                      float* __restrict__ mlg, int n) {
    int i = blockIdx.x * blockDim.x + threadIdx.x;
    if (i < n) mlg[i] = mrow[i] + __logf(16.0f * srow[i]);
}

// ------------------- QKV projection GEMM (hi/lo inputs, bf16 outputs) -------------------
__global__ __launch_bounds__(256) void k_qkv_gemm(
    const bf16* __restrict__ xh, const bf16* __restrict__ xl,
    const bf16* __restrict__ wh, const bf16* __restrict__ wl,
    const float* __restrict__ bq, const float* __restrict__ bk,
    const float* __restrict__ bv,
    bf16* __restrict__ qh, bf16* __restrict__ kh, bf16* __restrict__ vh)
{
    __shared__ __attribute__((aligned(16))) bf16 As[2][128 * 32];
    __shared__ __attribute__((aligned(16))) bf16 Bs[2][128 * 32];

    const int z  = blockIdx.z;           // 0=q,1=k,2=v
    const int m0 = blockIdx.x * 128;
    const int n0 = blockIdx.y * 128;
    const int tid = threadIdx.x, wave = tid >> 6, lane = tid & 63;
    const int wr = wave >> 1, wc = wave & 1;
    const int fr = lane & 15, fq = lane >> 4;
    const bf16* Wh = wh + (size_t)z * ED * ED;
    const bf16* Wl = wl + (size_t)z * ED * ED;

    const f32x4 z4 = {0.f, 0.f, 0.f, 0.f};
    f32x4 acc[4][4];
#pragma unroll
    for (int i = 0; i < 4; ++i)
#pragma unroll
        for (int j = 0; j < 4; ++j) acc[i][j] = z4;

#pragma unroll 1
    for (int kk = 0; kk < ED; kk += 32) {
#pragma unroll
        for (int r = 0; r < 2; ++r) {
            const int chunk = r * 256 + tid;
            const int row = chunk >> 2, c8 = (chunk & 3) * 8;
            const size_t ax = (size_t)(m0 + row) * ED + kk + c8;
            const size_t bx = (size_t)(n0 + row) * ED + kk + c8;
            const int db = (r * 256 + wave * 64) * 8;   // wave-uniform LDS base
            gl_lds16(xh + ax, &As[0][db]);
            gl_lds16(xl + ax, &As[1][db]);
            gl_lds16(Wh + bx, &Bs[0][db]);
            gl_lds16(Wl + bx, &Bs[1][db]);
        }
        __syncthreads();
        bf16x8 af[4][2], bfg[4][2];
#pragma unroll
        for (int i = 0; i < 4; ++i) {
            const int arow = wr * 64 + i * 16 + fr;
            af[i][0] = *(const bf16x8*)&As[0][arow * 32 + fq * 8];
            af[i][1] = *(const bf16x8*)&As[1][arow * 32 + fq * 8];
            const int brow = wc * 64 + i * 16 + fr;
            bfg[i][0] = *(const bf16x8*)&Bs[0][brow * 32 + fq * 8];
            bfg[i][1] = *(const bf16x8*)&Bs[1][brow * 32 + fq * 8];
        }
#pragma unroll
        for (int mi = 0; mi < 4; ++mi)
#pragma unroll
            for (int ni = 0; ni < 4; ++ni) {
                acc[mi][ni] = MFMA16(af[mi][0], bfg[ni][0], acc[mi][ni]);
                acc[mi][ni] = MFMA16(af[mi][0], bfg[ni][1], acc[mi][ni]);
                acc[mi][ni] = MFMA16(af[mi][1], bfg[ni][0], acc[mi][ni]);
            }
        __syncthreads();
    }

    const float* bias = (z == 0) ? bq : (z == 1) ? bk : bv;
#pragma unroll
    for (int mi = 0; mi < 4; ++mi) {
#pragma unroll
        for (int ni = 0; ni < 4; ++ni) {
            const int col = n0 + wc * 64 + ni * 16 + fr;
            const int hh = col >> 6, dd = col & 63;
#pragma unroll
            for (int j = 0; j < 4; ++j) {
                const int row = m0 + wr * 64 + mi * 16 + fq * 4 + j;
                float v = acc[mi][ni][j] + bias[col];
                const int nb = row >> 11, li = row & (SL - 1);
                const size_t off = (((size_t)nb * NH + hh) * SL + li) * HD + dd;
                if (z == 0) {
                    qh[off] = (bf16)(v * 0.125f);      // head_dim^-0.5
                } else if (z == 1) {
                    kh[off] = (bf16)v;
                } else {
                    vh[off] = (bf16)v;
                }
            }
        }
    }
}

// ------------------- output projection GEMM (hi/lo) -------------------
__global__ __launch_bounds__(256) void k_out_gemm(
    const bf16* __restrict__ ah, const bf16* __restrict__ al,
    const bf16* __restrict__ wh, const bf16* __restrict__ wl,
    const float* __restrict__ bo, float* __restrict__ out)
{
    __shared__ __attribute__((aligned(16))) bf16 As[2][128 * 32];
    __shared__ __attribute__((aligned(16))) bf16 Bs[2][128 * 32];

    const int m0 = blockIdx.x * 128;
    const int n0 = blockIdx.y * 128;
    const int tid = threadIdx.x, wave = tid >> 6, lane = tid & 63;
    const int wr = wave >> 1, wc = wave & 1;
    const int fr = lane & 15, fq = lane >> 4;

    const f32x4 z4 = {0.f, 0.f, 0.f, 0.f};
    f32x4 acc[4][4];
#pragma unroll
    for (int i = 0; i < 4; ++i)
#pragma unroll
        for (int j = 0; j < 4; ++j) acc[i][j] = z4;

#pragma unroll 1
    for (int kk = 0; kk < ED; kk += 32) {
#pragma unroll
        for (int r = 0; r < 2; ++r) {
            const int chunk = r * 256 + tid;
            const int row = chunk >> 2, c8 = (chunk & 3) * 8;
            const size_t ax = (size_t)(m0 + row) * ED + kk + c8;
            const size_t bx = (size_t)(n0 + row) * ED + kk + c8;
            const int db = (r * 256 + wave * 64) * 8;
            gl_lds16(ah + ax, &As[0][db]);
            gl_lds16(al + ax, &As[1][db]);
            gl_lds16(wh + bx, &Bs[0][db]);
            gl_lds16(wl + bx, &Bs[1][db]);
        }
        __syncthreads();
        bf16x8 af[4][2], bfg[4][2];
#pragma unroll
        for (int i = 0; i < 4; ++i) {
            const int arow = wr * 64 + i * 16 + fr;
            af[i][0] = *(const bf16x8*)&As[0][arow * 32 + fq * 8];
            af[i][1] = *(const bf16x8*)&As[1][arow * 32 + fq * 8];
            const int brow = wc * 64 + i * 16 + fr;
            bfg[i][0] = *(const bf16x8*)&Bs[0][brow * 32 + fq * 8];
            bfg[i][1] = *(const bf16x8*)&Bs[1][brow * 32 + fq * 8];
        }
#pragma unroll
        for (int mi = 0; mi < 4; ++mi)
#pragma unroll
            for (int ni = 0; ni < 4; ++ni) {
                acc[mi][ni] = MFMA16(af[mi][0], bfg[ni][0], acc[mi][ni]);
                acc[mi][ni] = MFMA16(af[mi][0], bfg[ni][1], acc[mi][ni]);
                acc[mi][ni] = MFMA16(af[mi][1], bfg[ni][0], acc[mi][ni]);
            }
        __syncthreads();
    }

#pragma unroll
    for (int mi = 0; mi < 4; ++mi)
#pragma unroll
        for (int ni = 0; ni < 4; ++ni) {
            const int col = n0 + wc * 64 + ni * 16 + fr;
#pragma unroll
            for (int j = 0; j < 4; ++j) {
                const int row = m0 + wr * 64 + mi * 16 + fq * 4 + j;
                out[(size_t)row * ED + col] = acc[mi][ni][j] + bo[col];
            }
        }
}

// ------------------- flash attention v9: v7 + mask bitpack (VGPR shave) -------------------
// Persistent mask regs (mkc[4]+mkn[4]) replaced by one 4-bit mask loaded per tile
// at the iteration top (mask array L1-resident; loads covered by staging+QK^T).
__global__ __launch_bounds__(256) void k_flash(
    const bf16* __restrict__ qh, const bf16* __restrict__ kh,
    const bf16* __restrict__ vh,
    const float* __restrict__ bias, const int* __restrict__ mask,
    bf16* __restrict__ ch, bf16* __restrict__ cl,
    float* __restrict__ mrow, float* __restrict__ srow)
{
    __shared__ __attribute__((aligned(16))) bf16 Ks[2][64 * 64];  // [key][d] swz, dbuf
    __shared__ __attribute__((aligned(16))) bf16 Vs[2][64 * 64];  // [d][key] swz, dbuf
    __shared__ __attribute__((aligned(16))) bf16 Ws[4][16 * 64];  // per-wave P, swz

    const int bid = blockIdx.x;
    const int xcd = bid & 7, local = bid >> 3;
    const int h = xcd * 2 + (local >> 6);
    const int rem = local & 63;
    const int qt = rem >> 2, n = rem & 3;

    const int tid = threadIdx.x, wave = tid >> 6, lane = tid & 63;
    const int fr = lane & 15, fq = lane >> 4;
    const int frx = fr & 7;
    const int q0 = qt * 128;
    const int qw = q0 + wave * 32;                  // wave's 32-row base
    const size_t hoff = ((size_t)n * NH + h) * SL * HD;
    const f32x4 z4 = {0.f, 0.f, 0.f, 0.f};

    bf16x8 qf0[2], qf1[2];
#pragma unroll
    for (int m = 0; m < 2; ++m) {
        const size_t qb = hoff + (size_t)(qw + m * 16 + fr) * HD + fq * 8;
        qf0[m] = *(const bf16x8*)(qh + qb);
        qf1[m] = *(const bf16x8*)(qh + qb + 32);
    }

    f32x4 o[2][4];
#pragma unroll
    for (int m = 0; m < 2; ++m)
#pragma unroll
        for (int f = 0; f < 4; ++f) o[m][f] = z4;
    float mj[2][4], sj[2][4];   // sj: LANE-LOCAL partial sums
#pragma unroll
    for (int m = 0; m < 2; ++m)
#pragma unroll
        for (int j = 0; j < 4; ++j) { mj[m][j] = -3e38f; sj[m][j] = 0.f; }

    const int* mkb = mask + n * SL;
    const float* bh = bias + (size_t)h * SL * SL;

    // ---- prologue ----
#pragma unroll
    for (int i = 0; i < 2; ++i) {
        const int li = i * 256 + tid;
        const int r = li >> 3, s = li & 7;
        gl_lds16(kh + hoff + (size_t)r * HD + (s ^ (r & 7)) * 8,
                 &Ks[0][(i * 256 + wave * 64) * 8]);
    }
    bf16x8 vr0 = *(const bf16x8*)(vh + hoff + (size_t)lane * HD + wave * 8);
    bf16x8 vr1 = *(const bf16x8*)(vh + hoff + (size_t)lane * HD + (wave + 4) * 8);
#pragma unroll
    for (int e = 0; e < 8; ++e) {
        const int d0 = wave * 8 + e, d1 = (wave + 4) * 8 + e;
        Vs[0][d0 * 64 + (((lane >> 3) ^ (d0 & 7)) << 3) + (lane & 7)] = vr0[e];
        Vs[0][d1 * 64 + (((lane >> 3) ^ (d1 & 7)) << 3) + (lane & 7)] = vr1[e];
    }
    vr0 = *(const bf16x8*)(vh + hoff + (size_t)(64 + lane) * HD + wave * 8);
    vr1 = *(const bf16x8*)(vh + hoff + (size_t)(64 + lane) * HD + (wave + 4) * 8);
    __syncthreads();   // drains K(0) DMA + Vs[0] writes

#pragma unroll 1
    for (int kt = 0; kt < 32; ++kt) {
        const int cur = kt & 1, nxt = cur ^ 1;
        const int kp1 = (kt < 31) ? kt + 1 : 31;
        const int kp2 = (kt < 30) ? kt + 2 : 31;

        // 0. mask bits for THIS tile (L1-hot; issued first, long cover)
        const int mw0 = mkb[kt * 64 + fr];
        const int mw1 = mkb[kt * 64 + 16 + fr];
        const int mw2 = mkb[kt * 64 + 32 + fr];
        const int mw3 = mkb[kt * 64 + 48 + fr];

        // 1. Vs[nxt] <- vr (V(kt+1))
#pragma unroll
        for (int e = 0; e < 8; ++e) {
            const int d0 = wave * 8 + e, d1 = (wave + 4) * 8 + e;
            Vs[nxt][d0 * 64 + (((lane >> 3) ^ (d0 & 7)) << 3) + (lane & 7)] = vr0[e];
            Vs[nxt][d1 * 64 + (((lane >> 3) ^ (d1 & 7)) << 3) + (lane & 7)] = vr1[e];
        }
        // 2. issue K(kt+1) -> Ks[nxt]
#pragma unroll
        for (int i = 0; i < 2; ++i) {
            const int li = i * 256 + tid;
            const int r = li >> 3, s = li & 7;
            gl_lds16(kh + hoff + (size_t)(kp1 * 64 + r) * HD + (s ^ (r & 7)) * 8,
                     &Ks[nxt][(i * 256 + wave * 64) * 8]);
        }
        // 3. V(kt+2) -> regs
        vr0 = *(const bf16x8*)(vh + hoff + (size_t)(kp2 * 64 + lane) * HD + wave * 8);
        vr1 = *(const bf16x8*)(vh + hoff + (size_t)(kp2 * 64 + lane) * HD + (wave + 4) * 8);
        const int mbits = (mw0 != 0 ? 1 : 0) | (mw1 != 0 ? 2 : 0)
                        | (mw2 != 0 ? 4 : 0) | (mw3 != 0 ? 8 : 0);

        // ---- compute: two independent 16-row chains ----
#pragma unroll
        for (int m = 0; m < 2; ++m) {
            float bfr[4][4];
#pragma unroll
            for (int nf = 0; nf < 4; ++nf)
#pragma unroll
                for (int j = 0; j < 4; ++j)
                    bfr[nf][j] = bh[(size_t)(qw + m * 16 + fq * 4 + j) * SL
                                    + kt * 64 + nf * 16 + fr];

            f32x4 sf[4];
            __builtin_amdgcn_s_setprio(1);
#pragma unroll
            for (int nf = 0; nf < 4; ++nf) {
                const bf16* kp = &Ks[cur][(nf * 16 + fr) * 64];
                const bf16x8 b0 = *(const bf16x8*)&kp[(fq ^ frx) * 8];
                const bf16x8 b1 = *(const bf16x8*)&kp[((fq + 4) ^ frx) * 8];
                f32x4 a = z4;
                a = MFMA16(qf0[m], b0, a);
                a = MFMA16(qf1[m], b1, a);
                sf[nf] = a;
            }
            __builtin_amdgcn_s_setprio(0);

            // bias + mask
#pragma unroll
            for (int nf = 0; nf < 4; ++nf) {
                const bool mk = (mbits >> nf) & 1;
#pragma unroll
                for (int j = 0; j < 4; ++j) {
                    float s = sf[nf][j] + bfr[nf][j];
                    sf[nf][j] = mk ? -1e30f : s;
                }
            }

            // defer-max online softmax (common path: no cross-lane ops)
            float tmax[4];
#pragma unroll
            for (int j = 0; j < 4; ++j)
                tmax[j] = fmaxf(fmaxf(sf[0][j], sf[1][j]), fmaxf(sf[2][j], sf[3][j]));
            bool need = false;
#pragma unroll
            for (int j = 0; j < 4; ++j)
                need = need || (tmax[j] > mj[m][j] + 8.0f);
            if (__any(need)) {
#pragma unroll
                for (int d = 1; d < 16; d <<= 1)
#pragma unroll
                    for (int j = 0; j < 4; ++j)
                        tmax[j] = fmaxf(tmax[j], __shfl_xor(tmax[j], d));
#pragma unroll
                for (int j = 0; j < 4; ++j) {
                    const float mn = fmaxf(mj[m][j], tmax[j]);
                    const float scale = __expf(mj[m][j] - mn);
                    mj[m][j] = mn;
                    sj[m][j] *= scale;
#pragma unroll
                    for (int f = 0; f < 4; ++f) o[m][f][j] *= scale;
                }
            }
#pragma unroll
            for (int nf = 0; nf < 4; ++nf)
#pragma unroll
                for (int j = 0; j < 4; ++j) {
                    const float w = __expf(sf[nf][j] - mj[m][j]);
                    sf[nf][j] = w;
                    sj[m][j] += w;
                }

            // P -> per-wave swizzled LDS tile (wave-local; reused across m)
#pragma unroll
            for (int nf = 0; nf < 4; ++nf)
#pragma unroll
                for (int j = 0; j < 4; ++j) {
                    const int row = fq * 4 + j, col = nf * 16 + fr;
                    Ws[wave][row * 64 + (((col >> 3) ^ (row & 7)) << 3) + (fr & 7)] =
                        (bf16)sf[nf][j];
                }
            const bf16* wp = &Ws[wave][fr * 64];
            const bf16x8 wa0 = *(const bf16x8*)&wp[(fq ^ frx) * 8];
            const bf16x8 wa1 = *(const bf16x8*)&wp[((fq + 4) ^ frx) * 8];
            __builtin_amdgcn_s_setprio(1);
#pragma unroll
            for (int f = 0; f < 4; ++f) {
                const bf16* vp = &Vs[cur][(f * 16 + fr) * 64];
                const bf16x8 vb0 = *(const bf16x8*)&vp[(fq ^ frx) * 8];
                const bf16x8 vb1 = *(const bf16x8*)&vp[((fq + 4) ^ frx) * 8];
                o[m][f] = MFMA16(wa0, vb0, o[m][f]);
                o[m][f] = MFMA16(wa1, vb1, o[m][f]);
            }
            __builtin_amdgcn_s_setprio(0);
        }

        __syncthreads();   // drains K(kt+1) DMA; fences Ks/Vs buffer swap
    }

    // epilogue: reduce lane-local sj across the 16-lane row group (once)
#pragma unroll
    for (int m = 0; m < 2; ++m)
#pragma unroll
        for (int d = 1; d < 16; d <<= 1)
#pragma unroll
            for (int j = 0; j < 4; ++j)
                sj[m][j] += __shfl_xor(sj[m][j], d);

    // context (hi/lo) + row stats, both m
#pragma unroll
    for (int m = 0; m < 2; ++m) {
#pragma unroll
        for (int j = 0; j < 4; ++j) {
            const float inv = 1.0f / sj[m][j];
            const int row = n * SL + qw + m * 16 + fq * 4 + j;
#pragma unroll
            for (int f = 0; f < 4; ++f) {
                const float v = o[m][f][j] * inv;
                const size_t off = (size_t)row * ED + h * HD + f * 16 + fr;
                const bf16 hv = (bf16)v;
                ch[off] = hv;
                cl[off] = (bf16)(v - (float)hv);
            }
        }
        if (fr == 0) {
#pragma unroll
            for (int j = 0; j < 4; ++j) {
                const int r = qw + m * 16 + fq * 4 + j;
                mrow[((size_t)n * NH + h) * SL + r] = mj[m][j];
                srow[((size_t)n * NH + h) * SL + r] = sj[m][j];
            }
        }
    }
}

// ------------------- head-averaged weights v5: KT=64, mlg precomputed, mk bitpacked -------------------
__global__ __launch_bounds__(256) void k_avg(
    const bf16* __restrict__ qh, const bf16* __restrict__ kh,
    const float* __restrict__ bias, const int* __restrict__ mask,
    const float* __restrict__ mlg, float* __restrict__ avg)
{
    __shared__ __attribute__((aligned(16))) bf16 Qs[2][64 * 64];  // 8KB x2
    __shared__ __attribute__((aligned(16))) bf16 Ks2[2][64 * 64]; // 8KB x2

    const int qt = blockIdx.x, kt = blockIdx.y;
    const int tid = threadIdx.x, wave = tid >> 6, lane = tid & 63;
    const int fr = lane & 15, fq = lane >> 4;
    const int frx = fr & 7;
    const int q0 = qt * 64, k0 = kt * 64;
    const int qr = q0 + wave * 16;
    const f32x4 z4 = {0.f, 0.f, 0.f, 0.f};

    f32x4 acc[4][4];   // [nn][nf] -- all compile-time indices
#pragma unroll
    for (int nn = 0; nn < 4; ++nn)
#pragma unroll
        for (int nf = 0; nf < 4; ++nf) acc[nn][nf] = z4;

    // bitpack mask: bit (nn*4+nf)
    int mkbits = 0;
#pragma unroll
    for (int nn = 0; nn < 4; ++nn)
#pragma unroll
        for (int nf = 0; nf < 4; ++nf)
            mkbits |= (mask[nn * SL + k0 + nf * 16 + fr] != 0 ? 1 : 0) << (nn * 4 + nf);

    auto stage = [&](int hh, int nn2, int b) {
        const bf16* qb = qh + (((size_t)nn2 * NH + hh) * SL + q0) * HD;
        const bf16* kb = kh + (((size_t)nn2 * NH + hh) * SL + k0) * HD;
#pragma unroll
        for (int i = 0; i < 2; ++i) {
            const int li = i * 256 + tid;
            const int r = li >> 3, s = li & 7;
            gl_lds16(qb + (size_t)r * HD + (s ^ (r & 7)) * 8,
                     &Qs[b][(i * 256 + wave * 64) * 8]);
            gl_lds16(kb + (size_t)r * HD + (s ^ (r & 7)) * 8,
                     &Ks2[b][(i * 256 + wave * 64) * 8]);
        }
    };

    stage(0, 0, 0);
    __syncthreads();

    int cur = 0;
#pragma unroll 1
    for (int h = 0; h < NH; ++h) {
        float bfr[4][4];
#pragma unroll
        for (int nf = 0; nf < 4; ++nf)
#pragma unroll
            for (int j = 0; j < 4; ++j)
                bfr[nf][j] = bias[((size_t)h * SL + qr + fq * 4 + j) * SL + k0 + nf * 16 + fr];

#pragma unroll
        for (int nn = 0; nn < 4; ++nn) {
            const int ih = h * 4 + nn;
            const int nxt = cur ^ 1;
            if (ih < 63) stage((ih + 1) >> 2, (ih + 1) & 3, nxt);

            const size_t sidx = ((size_t)nn * NH + h) * SL + qr + fq * 4;
            const f32x4 mlgv = *(const f32x4*)(mlg + sidx);

            const bf16* qp = &Qs[cur][(wave * 16 + fr) * 64];
            const bf16x8 qf0 = *(const bf16x8*)&qp[(fq ^ frx) * 8];
            const bf16x8 qf1 = *(const bf16x8*)&qp[((fq + 4) ^ frx) * 8];
#pragma unroll
            for (int nf = 0; nf < 4; ++nf) {
                const bf16* kp = &Ks2[cur][(nf * 16 + fr) * 64];
                const bf16x8 b0 = *(const bf16x8*)&kp[(fq ^ frx) * 8];
                const bf16x8 b1 = *(const bf16x8*)&kp[((fq + 4) ^ frx) * 8];
                f32x4 a = z4;
                a = MFMA16(qf0, b0, a);
                a = MFMA16(qf1, b1, a);
                const bool mk = (mkbits >> (nn * 4 + nf)) & 1;
#pragma unroll
                for (int j = 0; j < 4; ++j) {
                    const float w = mk ? 0.f
                        : __expf(a[j] + bfr[nf][j] - mlgv[j]);
                    acc[nn][nf][j] += w;
                }
            }
            __syncthreads();
            cur = nxt;
        }
    }

#pragma unroll
    for (int nn = 0; nn < 4; ++nn)
#pragma unroll
        for (int j = 0; j < 4; ++j) {
            const size_t rowoff = ((size_t)nn * SL + qr + fq * 4 + j) * SL;
#pragma unroll
            for (int nf = 0; nf < 4; ++nf)
                avg[rowoff + k0 + nf * 16 + fr] = acc[nn][nf][j];
        }
}

// ------------------- launcher -------------------
extern "C" void kernel_launch(void* const* d_in, const int* in_sizes, int n_in,
                              void* d_out, int out_size, void* d_ws, size_t ws_size,
                              hipStream_t stream)
{
    (void)in_sizes; (void)n_in; (void)out_size; (void)ws_size;
    const float* query = (const float*)d_in[0];
    const float* bias  = (const float*)d_in[1];
    const int* mask = (const int*)d_in[2];
    const float* Wq = (const float*)d_in[3];
    const float* bq = (const float*)d_in[4];
    const float* Wk = (const float*)d_in[5];
    const float* bk = (const float*)d_in[6];
    const float* Wv = (const float*)d_in[7];
    const float* bv = (const float*)d_in[8];
    const float* Wo = (const float*)d_in[9];
    const float* bo = (const float*)d_in[10];
    float* out0 = (float*)d_out;                      // [N,L,E]
    float* out1 = out0 + (size_t)MR * ED;             // [N,L,L]

    char* p = (char*)d_ws;
    auto carve = [&](size_t bytes) {
        char* r = p;
        p += (bytes + 255) & ~(size_t)255;
        return r;
    };
    const size_t QKVB = (size_t)NB * NH * SL * HD * 2;   // 16.78 MB
    bf16* xh = (bf16*)carve((size_t)MR * ED * 2);
    bf16* xl = (bf16*)carve((size_t)MR * ED * 2);
    bf16* wh = (bf16*)carve((size_t)4 * ED * ED * 2);
    bf16* wl = (bf16*)carve((size_t)4 * ED * ED * 2);
    bf16* qh = (bf16*)carve(QKVB);
    bf16* kh = (bf16*)carve(QKVB);
    bf16* vh = (bf16*)carve(QKVB);
    float* mrow = (float*)carve((size_t)NB * NH * SL * 4);
    float* srow = (float*)carve((size_t)NB * NH * SL * 4);
    float* mlg  = (float*)carve((size_t)NB * NH * SL * 4);
    bf16* ch = (bf16*)carve((size_t)MR * ED * 2);
    bf16* cl = (bf16*)carve((size_t)MR * ED * 2);

    // 1. split inputs to hi/lo bf16
    {
        const int n4 = MR * ED / 4;
        k_split<<<(n4 + 255) / 256, 256, 0, stream>>>(query, xh, xl, n4);
        const int w4 = ED * ED / 4;
        const float* Ws4[4] = {Wq, Wk, Wv, Wo};
        for (int i = 0; i < 4; ++i)
            k_split<<<(w4 + 255) / 256, 256, 0, stream>>>(
                Ws4[i], wh + (size_t)i * ED * ED, wl + (size_t)i * ED * ED, w4);
    }
    // 2. QKV projections
    k_qkv_gemm<<<dim3(MR / 128, ED / 128, 3), 256, 0, stream>>>(
        xh, xl, wh, wl, bq, bk, bv, qh, kh, vh);
    // 3. flash attention + row stats + context (QBLK=128 -> 1024 blocks)
    k_flash<<<dim3(1024), 256, 0, stream>>>(
        qh, kh, vh, bias, mask, ch, cl, mrow, srow);
    // 3b. mlg = m + ln(16 s)
    {
        const int nst = NB * NH * SL;
        k_mlg<<<(nst + 255) / 256, 256, 0, stream>>>(mrow, srow, mlg, nst);
    }
    // 4. head-averaged attention weights (64x64 tiles)
    k_avg<<<dim3(SL / 64, SL / 64), 256, 0, stream>>>(
        qh, kh, bias, mask, mlg, out1);
    // 5. output projection
    k_out_gemm<<<dim3(MR / 128, ED / 128), 256, 0, stream>>>(
        ch, cl, wh + (size_t)3 * ED * ED, wl + (size_t)3 * ED * ED, bo, out0);
}

// Round 17
// 604.398 us; speedup vs baseline: 1.3011x; 1.0228x over previous
//
#include <hip/hip_runtime.h>
#include <stdint.h>

typedef __bf16 bf16;
typedef __bf16 bf16x4 __attribute__((ext_vector_type(4)));
typedef __bf16 bf16x8 __attribute__((ext_vector_type(8)));
typedef float f32x4 __attribute__((ext_vector_type(4)));

#define MFMA16(a, b, c) __builtin_amdgcn_mfma_f32_16x16x32_bf16((a), (b), (c), 0, 0, 0)

static constexpr int NB = 4;      // batch
static constexpr int NH = 16;     // heads
static constexpr int SL = 2048;   // seq len
static constexpr int HD = 64;     // head dim
static constexpr int ED = 1024;   // embed
static constexpr int MR = NB * SL; // 8192 rows

__device__ __forceinline__ void gl_lds16(const void* g, void* l) {
    __builtin_amdgcn_global_load_lds(
        (const __attribute__((address_space(1))) unsigned int*)g,
        (__attribute__((address_space(3))) unsigned int*)l, 16, 0, 0);
}

// ------------------- f32 -> bf16 hi/lo split -------------------
__global__ void k_split(const float* __restrict__ src, bf16* __restrict__ hi,
                        bf16* __restrict__ lo, int n4) {
    int i = blockIdx.x * blockDim.x + threadIdx.x;
    if (i >= n4) return;
    const float4 v = ((const float4*)src)[i];
    float vv[4] = {v.x, v.y, v.z, v.w};
    bf16x4 hv, lv;
#pragma unroll
    for (int e = 0; e < 4; ++e) {
        bf16 h = (bf16)vv[e];
        hv[e] = h;
        lv[e] = (bf16)(vv[e] - (float)h);
    }
    ((bf16x4*)hi)[i] = hv;
    ((bf16x4*)lo)[i] = lv;
}

// ------------------- mlg precompute: mlg = m + ln(16 s) -------------------
__global__ void k_mlg(const float* __restrict__ mrow, const float* __restrict__ srow,
                      float* __restrict__ mlg, int n) {
    int i = blockIdx.x * blockDim.x + threadIdx.x;
    if (i < n) mlg[i] = mrow[i] + __logf(16.0f * srow[i]);
}

// ------------------- QKV projection GEMM (hi/lo inputs, bf16 outputs) -------------------
__global__ __launch_bounds__(256) void k_qkv_gemm(
    const bf16* __restrict__ xh, const bf16* __restrict__ xl,
    const bf16* __restrict__ wh, const bf16* __restrict__ wl,
    const float* __restrict__ bq, const float* __restrict__ bk,
    const float* __restrict__ bv,
    bf16* __restrict__ qh, bf16* __restrict__ kh, bf16* __restrict__ vh)
{
    __shared__ __attribute__((aligned(16))) bf16 As[2][128 * 32];
    __shared__ __attribute__((aligned(16))) bf16 Bs[2][128 * 32];

    const int z  = blockIdx.z;           // 0=q,1=k,2=v
    const int m0 = blockIdx.x * 128;
    const int n0 = blockIdx.y * 128;
    const int tid = threadIdx.x, wave = tid >> 6, lane = tid & 63;
    const int wr = wave >> 1, wc = wave & 1;
    const int fr = lane & 15, fq = lane >> 4;
    const bf16* Wh = wh + (size_t)z * ED * ED;
    const bf16* Wl = wl + (size_t)z * ED * ED;

    const f32x4 z4 = {0.f, 0.f, 0.f, 0.f};
    f32x4 acc[4][4];
#pragma unroll
    for (int i = 0; i < 4; ++i)
#pragma unroll
        for (int j = 0; j < 4; ++j) acc[i][j] = z4;

#pragma unroll 1
    for (int kk = 0; kk < ED; kk += 32) {
#pragma unroll
        for (int r = 0; r < 2; ++r) {
            const int chunk = r * 256 + tid;
            const int row = chunk >> 2, c8 = (chunk & 3) * 8;
            const size_t ax = (size_t)(m0 + row) * ED + kk + c8;
            const size_t bx = (size_t)(n0 + row) * ED + kk + c8;
            const int db = (r * 256 + wave * 64) * 8;   // wave-uniform LDS base
            gl_lds16(xh + ax, &As[0][db]);
            gl_lds16(xl + ax, &As[1][db]);
            gl_lds16(Wh + bx, &Bs[0][db]);
            gl_lds16(Wl + bx, &Bs[1][db]);
        }
        __syncthreads();
        bf16x8 af[4][2], bfg[4][2];
#pragma unroll
        for (int i = 0; i < 4; ++i) {
            const int arow = wr * 64 + i * 16 + fr;
            af[i][0] = *(const bf16x8*)&As[0][arow * 32 + fq * 8];
            af[i][1] = *(const bf16x8*)&As[1][arow * 32 + fq * 8];
            const int brow = wc * 64 + i * 16 + fr;
            bfg[i][0] = *(const bf16x8*)&Bs[0][brow * 32 + fq * 8];
            bfg[i][1] = *(const bf16x8*)&Bs[1][brow * 32 + fq * 8];
        }
#pragma unroll
        for (int mi = 0; mi < 4; ++mi)
#pragma unroll
            for (int ni = 0; ni < 4; ++ni) {
                acc[mi][ni] = MFMA16(af[mi][0], bfg[ni][0], acc[mi][ni]);
                acc[mi][ni] = MFMA16(af[mi][0], bfg[ni][1], acc[mi][ni]);
                acc[mi][ni] = MFMA16(af[mi][1], bfg[ni][0], acc[mi][ni]);
            }
        __syncthreads();
    }

    const float* bias = (z == 0) ? bq : (z == 1) ? bk : bv;
#pragma unroll
    for (int mi = 0; mi < 4; ++mi) {
#pragma unroll
        for (int ni = 0; ni < 4; ++ni) {
            const int col = n0 + wc * 64 + ni * 16 + fr;
            const int hh = col >> 6, dd = col & 63;
#pragma unroll
            for (int j = 0; j < 4; ++j) {
                const int row = m0 + wr * 64 + mi * 16 + fq * 4 + j;
                float v = acc[mi][ni][j] + bias[col];
                const int nb = row >> 11, li = row & (SL - 1);
                const size_t off = (((size_t)nb * NH + hh) * SL + li) * HD + dd;
                if (z == 0) {
                    qh[off] = (bf16)(v * 0.125f);      // head_dim^-0.5
                } else if (z == 1) {
                    kh[off] = (bf16)v;
                } else {
                    vh[off] = (bf16)v;
                }
            }
        }
    }
}

// ------------------- output projection GEMM (hi/lo) -------------------
__global__ __launch_bounds__(256) void k_out_gemm(
    const bf16* __restrict__ ah, const bf16* __restrict__ al,
    const bf16* __restrict__ wh, const bf16* __restrict__ wl,
    const float* __restrict__ bo, float* __restrict__ out)
{
    __shared__ __attribute__((aligned(16))) bf16 As[2][128 * 32];
    __shared__ __attribute__((aligned(16))) bf16 Bs[2][128 * 32];

    const int m0 = blockIdx.x * 128;
    const int n0 = blockIdx.y * 128;
    const int tid = threadIdx.x, wave = tid >> 6, lane = tid & 63;
    const int wr = wave >> 1, wc = wave & 1;
    const int fr = lane & 15, fq = lane >> 4;

    const f32x4 z4 = {0.f, 0.f, 0.f, 0.f};
    f32x4 acc[4][4];
#pragma unroll
    for (int i = 0; i < 4; ++i)
#pragma unroll
        for (int j = 0; j < 4; ++j) acc[i][j] = z4;

#pragma unroll 1
    for (int kk = 0; kk < ED; kk += 32) {
#pragma unroll
        for (int r = 0; r < 2; ++r) {
            const int chunk = r * 256 + tid;
            const int row = chunk >> 2, c8 = (chunk & 3) * 8;
            const size_t ax = (size_t)(m0 + row) * ED + kk + c8;
            const size_t bx = (size_t)(n0 + row) * ED + kk + c8;
            const int db = (r * 256 + wave * 64) * 8;
            gl_lds16(ah + ax, &As[0][db]);
            gl_lds16(al + ax, &As[1][db]);
            gl_lds16(wh + bx, &Bs[0][db]);
            gl_lds16(wl + bx, &Bs[1][db]);
        }
        __syncthreads();
        bf16x8 af[4][2], bfg[4][2];
#pragma unroll
        for (int i = 0; i < 4; ++i) {
            const int arow = wr * 64 + i * 16 + fr;
            af[i][0] = *(const bf16x8*)&As[0][arow * 32 + fq * 8];
            af[i][1] = *(const bf16x8*)&As[1][arow * 32 + fq * 8];
            const int brow = wc * 64 + i * 16 + fr;
            bfg[i][0] = *(const bf16x8*)&Bs[0][brow * 32 + fq * 8];
            bfg[i][1] = *(const bf16x8*)&Bs[1][brow * 32 + fq * 8];
        }
#pragma unroll
        for (int mi = 0; mi < 4; ++mi)
#pragma unroll
            for (int ni = 0; ni < 4; ++ni) {
                acc[mi][ni] = MFMA16(af[mi][0], bfg[ni][0], acc[mi][ni]);
                acc[mi][ni] = MFMA16(af[mi][0], bfg[ni][1], acc[mi][ni]);
                acc[mi][ni] = MFMA16(af[mi][1], bfg[ni][0], acc[mi][ni]);
            }
        __syncthreads();
    }

#pragma unroll
    for (int mi = 0; mi < 4; ++mi)
#pragma unroll
        for (int ni = 0; ni < 4; ++ni) {
            const int col = n0 + wc * 64 + ni * 16 + fr;
#pragma unroll
            for (int j = 0; j < 4; ++j) {
                const int row = m0 + wr * 64 + mi * 16 + fq * 4 + j;
                out[(size_t)row * ED + col] = acc[mi][ni][j] + bo[col];
            }
        }
}

// ------------------- flash attention v9 (unchanged from round 16) -------------------
__global__ __launch_bounds__(256) void k_flash(
    const bf16* __restrict__ qh, const bf16* __restrict__ kh,
    const bf16* __restrict__ vh,
    const float* __restrict__ bias, const int* __restrict__ mask,
    bf16* __restrict__ ch, bf16* __restrict__ cl,
    float* __restrict__ mrow, float* __restrict__ srow)
{
    __shared__ __attribute__((aligned(16))) bf16 Ks[2][64 * 64];  // [key][d] swz, dbuf
    __shared__ __attribute__((aligned(16))) bf16 Vs[2][64 * 64];  // [d][key] swz, dbuf
    __shared__ __attribute__((aligned(16))) bf16 Ws[4][16 * 64];  // per-wave P, swz

    const int bid = blockIdx.x;
    const int xcd = bid & 7, local = bid >> 3;
    const int h = xcd * 2 + (local >> 6);
    const int rem = local & 63;
    const int qt = rem >> 2, n = rem & 3;

    const int tid = threadIdx.x, wave = tid >> 6, lane = tid & 63;
    const int fr = lane & 15, fq = lane >> 4;
    const int frx = fr & 7;
    const int q0 = qt * 128;
    const int qw = q0 + wave * 32;                  // wave's 32-row base
    const size_t hoff = ((size_t)n * NH + h) * SL * HD;
    const f32x4 z4 = {0.f, 0.f, 0.f, 0.f};

    bf16x8 qf0[2], qf1[2];
#pragma unroll
    for (int m = 0; m < 2; ++m) {
        const size_t qb = hoff + (size_t)(qw + m * 16 + fr) * HD + fq * 8;
        qf0[m] = *(const bf16x8*)(qh + qb);
        qf1[m] = *(const bf16x8*)(qh + qb + 32);
    }

    f32x4 o[2][4];
#pragma unroll
    for (int m = 0; m < 2; ++m)
#pragma unroll
        for (int f = 0; f < 4; ++f) o[m][f] = z4;
    float mj[2][4], sj[2][4];   // sj: LANE-LOCAL partial sums
#pragma unroll
    for (int m = 0; m < 2; ++m)
#pragma unroll
        for (int j = 0; j < 4; ++j) { mj[m][j] = -3e38f; sj[m][j] = 0.f; }

    const int* mkb = mask + n * SL;
    const float* bh = bias + (size_t)h * SL * SL;

    // ---- prologue ----
#pragma unroll
    for (int i = 0; i < 2; ++i) {
        const int li = i * 256 + tid;
        const int r = li >> 3, s = li & 7;
        gl_lds16(kh + hoff + (size_t)r * HD + (s ^ (r & 7)) * 8,
                 &Ks[0][(i * 256 + wave * 64) * 8]);
    }
    bf16x8 vr0 = *(const bf16x8*)(vh + hoff + (size_t)lane * HD + wave * 8);
    bf16x8 vr1 = *(const bf16x8*)(vh + hoff + (size_t)lane * HD + (wave + 4) * 8);
#pragma unroll
    for (int e = 0; e < 8; ++e) {
        const int d0 = wave * 8 + e, d1 = (wave + 4) * 8 + e;
        Vs[0][d0 * 64 + (((lane >> 3) ^ (d0 & 7)) << 3) + (lane & 7)] = vr0[e];
        Vs[0][d1 * 64 + (((lane >> 3) ^ (d1 & 7)) << 3) + (lane & 7)] = vr1[e];
    }
    vr0 = *(const bf16x8*)(vh + hoff + (size_t)(64 + lane) * HD + wave * 8);
    vr1 = *(const bf16x8*)(vh + hoff + (size_t)(64 + lane) * HD + (wave + 4) * 8);
    __syncthreads();   // drains K(0) DMA + Vs[0] writes

#pragma unroll 1
    for (int kt = 0; kt < 32; ++kt) {
        const int cur = kt & 1, nxt = cur ^ 1;
        const int kp1 = (kt < 31) ? kt + 1 : 31;
        const int kp2 = (kt < 30) ? kt + 2 : 31;

        // 0. mask bits for THIS tile (L1-hot; issued first, long cover)
        const int mw0 = mkb[kt * 64 + fr];
        const int mw1 = mkb[kt * 64 + 16 + fr];
        const int mw2 = mkb[kt * 64 + 32 + fr];
        const int mw3 = mkb[kt * 64 + 48 + fr];

        // 1. Vs[nxt] <- vr (V(kt+1))
#pragma unroll
        for (int e = 0; e < 8; ++e) {
            const int d0 = wave * 8 + e, d1 = (wave + 4) * 8 + e;
            Vs[nxt][d0 * 64 + (((lane >> 3) ^ (d0 & 7)) << 3) + (lane & 7)] = vr0[e];
            Vs[nxt][d1 * 64 + (((lane >> 3) ^ (d1 & 7)) << 3) + (lane & 7)] = vr1[e];
        }
        // 2. issue K(kt+1) -> Ks[nxt]
#pragma unroll
        for (int i = 0; i < 2; ++i) {
            const int li = i * 256 + tid;
            const int r = li >> 3, s = li & 7;
            gl_lds16(kh + hoff + (size_t)(kp1 * 64 + r) * HD + (s ^ (r & 7)) * 8,
                     &Ks[nxt][(i * 256 + wave * 64) * 8]);
        }
        // 3. V(kt+2) -> regs
        vr0 = *(const bf16x8*)(vh + hoff + (size_t)(kp2 * 64 + lane) * HD + wave * 8);
        vr1 = *(const bf16x8*)(vh + hoff + (size_t)(kp2 * 64 + lane) * HD + (wave + 4) * 8);
        const int mbits = (mw0 != 0 ? 1 : 0) | (mw1 != 0 ? 2 : 0)
                        | (mw2 != 0 ? 4 : 0) | (mw3 != 0 ? 8 : 0);

        // ---- compute: two independent 16-row chains ----
#pragma unroll
        for (int m = 0; m < 2; ++m) {
            float bfr[4][4];
#pragma unroll
            for (int nf = 0; nf < 4; ++nf)
#pragma unroll
                for (int j = 0; j < 4; ++j)
                    bfr[nf][j] = bh[(size_t)(qw + m * 16 + fq * 4 + j) * SL
                                    + kt * 64 + nf * 16 + fr];

            f32x4 sf[4];
            __builtin_amdgcn_s_setprio(1);
#pragma unroll
            for (int nf = 0; nf < 4; ++nf) {
                const bf16* kp = &Ks[cur][(nf * 16 + fr) * 64];
                const bf16x8 b0 = *(const bf16x8*)&kp[(fq ^ frx) * 8];
                const bf16x8 b1 = *(const bf16x8*)&kp[((fq + 4) ^ frx) * 8];
                f32x4 a = z4;
                a = MFMA16(qf0[m], b0, a);
                a = MFMA16(qf1[m], b1, a);
                sf[nf] = a;
            }
            __builtin_amdgcn_s_setprio(0);

            // bias + mask
#pragma unroll
            for (int nf = 0; nf < 4; ++nf) {
                const bool mk = (mbits >> nf) & 1;
#pragma unroll
                for (int j = 0; j < 4; ++j) {
                    float s = sf[nf][j] + bfr[nf][j];
                    sf[nf][j] = mk ? -1e30f : s;
                }
            }

            // defer-max online softmax (common path: no cross-lane ops)
            float tmax[4];
#pragma unroll
            for (int j = 0; j < 4; ++j)
                tmax[j] = fmaxf(fmaxf(sf[0][j], sf[1][j]), fmaxf(sf[2][j], sf[3][j]));
            bool need = false;
#pragma unroll
            for (int j = 0; j < 4; ++j)
                need = need || (tmax[j] > mj[m][j] + 8.0f);
            if (__any(need)) {
#pragma unroll
                for (int d = 1; d < 16; d <<= 1)
#pragma unroll
                    for (int j = 0; j < 4; ++j)
                        tmax[j] = fmaxf(tmax[j], __shfl_xor(tmax[j], d));
#pragma unroll
                for (int j = 0; j < 4; ++j) {
                    const float mn = fmaxf(mj[m][j], tmax[j]);
                    const float scale = __expf(mj[m][j] - mn);
                    mj[m][j] = mn;
                    sj[m][j] *= scale;
#pragma unroll
                    for (int f = 0; f < 4; ++f) o[m][f][j] *= scale;
                }
            }
#pragma unroll
            for (int nf = 0; nf < 4; ++nf)
#pragma unroll
                for (int j = 0; j < 4; ++j) {
                    const float w = __expf(sf[nf][j] - mj[m][j]);
                    sf[nf][j] = w;
                    sj[m][j] += w;
                }

            // P -> per-wave swizzled LDS tile (wave-local; reused across m)
#pragma unroll
            for (int nf = 0; nf < 4; ++nf)
#pragma unroll
                for (int j = 0; j < 4; ++j) {
                    const int row = fq * 4 + j, col = nf * 16 + fr;
                    Ws[wave][row * 64 + (((col >> 3) ^ (row & 7)) << 3) + (fr & 7)] =
                        (bf16)sf[nf][j];
                }
            const bf16* wp = &Ws[wave][fr * 64];
            const bf16x8 wa0 = *(const bf16x8*)&wp[(fq ^ frx) * 8];
            const bf16x8 wa1 = *(const bf16x8*)&wp[((fq + 4) ^ frx) * 8];
            __builtin_amdgcn_s_setprio(1);
#pragma unroll
            for (int f = 0; f < 4; ++f) {
                const bf16* vp = &Vs[cur][(f * 16 + fr) * 64];
                const bf16x8 vb0 = *(const bf16x8*)&vp[(fq ^ frx) * 8];
                const bf16x8 vb1 = *(const bf16x8*)&vp[((fq + 4) ^ frx) * 8];
                o[m][f] = MFMA16(wa0, vb0, o[m][f]);
                o[m][f] = MFMA16(wa1, vb1, o[m][f]);
            }
            __builtin_amdgcn_s_setprio(0);
        }

        __syncthreads();   // drains K(kt+1) DMA; fences Ks/Vs buffer swap
    }

    // epilogue: reduce lane-local sj across the 16-lane row group (once)
#pragma unroll
    for (int m = 0; m < 2; ++m)
#pragma unroll
        for (int d = 1; d < 16; d <<= 1)
#pragma unroll
            for (int j = 0; j < 4; ++j)
                sj[m][j] += __shfl_xor(sj[m][j], d);

    // context (hi/lo) + row stats, both m
#pragma unroll
    for (int m = 0; m < 2; ++m) {
#pragma unroll
        for (int j = 0; j < 4; ++j) {
            const float inv = 1.0f / sj[m][j];
            const int row = n * SL + qw + m * 16 + fq * 4 + j;
#pragma unroll
            for (int f = 0; f < 4; ++f) {
                const float v = o[m][f][j] * inv;
                const size_t off = (size_t)row * ED + h * HD + f * 16 + fr;
                const bf16 hv = (bf16)v;
                ch[off] = hv;
                cl[off] = (bf16)(v - (float)hv);
            }
        }
        if (fr == 0) {
#pragma unroll
            for (int j = 0; j < 4; ++j) {
                const int r = qw + m * 16 + fq * 4 + j;
                mrow[((size_t)n * NH + h) * SL + r] = mj[m][j];
                srow[((size_t)n * NH + h) * SL + r] = sj[m][j];
            }
        }
    }
}

// ------------------- head-averaged weights v6: Q direct-to-reg, K-only LDS -------------------
// Q rows are wave-private -> loaded straight to registers with 1-step prefetch
// (static parity indexing). LDS holds only K (2x8KB double buffer).
__global__ __launch_bounds__(256) void k_avg(
    const bf16* __restrict__ qh, const bf16* __restrict__ kh,
    const float* __restrict__ bias, const int* __restrict__ mask,
    const float* __restrict__ mlg, float* __restrict__ avg)
{
    __shared__ __attribute__((aligned(16))) bf16 Ks2[2][64 * 64]; // 8KB x2

    const int qt = blockIdx.x, kt = blockIdx.y;
    const int tid = threadIdx.x, wave = tid >> 6, lane = tid & 63;
    const int fr = lane & 15, fq = lane >> 4;
    const int frx = fr & 7;
    const int q0 = qt * 64, k0 = kt * 64;
    const int qr = q0 + wave * 16;
    const f32x4 z4 = {0.f, 0.f, 0.f, 0.f};

    f32x4 acc[4][4];   // [nn][nf] -- all compile-time indices
#pragma unroll
    for (int nn = 0; nn < 4; ++nn)
#pragma unroll
        for (int nf = 0; nf < 4; ++nf) acc[nn][nf] = z4;

    // bitpack mask: bit (nn*4+nf)
    int mkbits = 0;
#pragma unroll
    for (int nn = 0; nn < 4; ++nn)
#pragma unroll
        for (int nf = 0; nf < 4; ++nf)
            mkbits |= (mask[nn * SL + k0 + nf * 16 + fr] != 0 ? 1 : 0) << (nn * 4 + nf);

    auto stageK = [&](int hh, int nn2, int b) {
        const bf16* kb = kh + (((size_t)nn2 * NH + hh) * SL + k0) * HD;
#pragma unroll
        for (int i = 0; i < 2; ++i) {
            const int li = i * 256 + tid;
            const int r = li >> 3, s = li & 7;
            gl_lds16(kb + (size_t)r * HD + (s ^ (r & 7)) * 8,
                     &Ks2[b][(i * 256 + wave * 64) * 8]);
        }
    };
    auto loadQ = [&](int hh, int nn2, bf16x8& a0, bf16x8& a1) {
        const bf16* qb = qh + ((((size_t)nn2 * NH + hh) * SL + qr + fr) * HD) + fq * 8;
        a0 = *(const bf16x8*)qb;
        a1 = *(const bf16x8*)(qb + 32);
    };
    auto loadMlg = [&](int hh, int nn2) -> f32x4 {
        return *(const f32x4*)(mlg + ((size_t)nn2 * NH + hh) * SL + qr + fq * 4);
    };

    // prologue: K(0,0) -> Ks2[0]; Q(0,0) + mlg(0,0) -> regs
    stageK(0, 0, 0);
    bf16x8 qcA, qcB;
    loadQ(0, 0, qcA, qcB);
    f32x4 mlgc = loadMlg(0, 0);
    __syncthreads();

#pragma unroll 1
    for (int h = 0; h < NH; ++h) {
        // bias tile rows for this h (consumed over 4 nn steps)
        float bfr[4][4];
#pragma unroll
        for (int nf = 0; nf < 4; ++nf)
#pragma unroll
            for (int j = 0; j < 4; ++j)
                bfr[nf][j] = bias[((size_t)h * SL + qr + fq * 4 + j) * SL + k0 + nf * 16 + fr];

#pragma unroll
        for (int nn = 0; nn < 4; ++nn) {
            const int ih = h * 4 + nn;           // unrolled: ih&1 is compile-time
            const int buf = ih & 1;

            // prefetch next step: K -> LDS[buf^1], Q + mlg -> regs
            bf16x8 qnA, qnB;
            f32x4 mlgn = mlgc;
            if (ih < 63) {
                const int jh = (ih + 1) >> 2, jnn = (ih + 1) & 3;
                stageK(jh, jnn, buf ^ 1);
                loadQ(jh, jnn, qnA, qnB);
                mlgn = loadMlg(jh, jnn);
            } else {
                qnA = qcA; qnB = qcB;
            }

            // compute on current (qcA/qcB, Ks2[buf], mlgc)
#pragma unroll
            for (int nf = 0; nf < 4; ++nf) {
                const bf16* kp = &Ks2[buf][(nf * 16 + fr) * 64];
                const bf16x8 b0 = *(const bf16x8*)&kp[(fq ^ frx) * 8];
                const bf16x8 b1 = *(const bf16x8*)&kp[((fq + 4) ^ frx) * 8];
                f32x4 a = z4;
                a = MFMA16(qcA, b0, a);
                a = MFMA16(qcB, b1, a);
                const bool mk = (mkbits >> (nn * 4 + nf)) & 1;
#pragma unroll
                for (int j = 0; j < 4; ++j) {
                    const float w = mk ? 0.f
                        : __expf(a[j] + bfr[nf][j] - mlgc[j]);
                    acc[nn][nf][j] += w;
                }
            }
            __syncthreads();    // drains next-K DMA; fences buffer swap
            qcA = qnA; qcB = qnB; mlgc = mlgn;
        }
    }

#pragma unroll
    for (int nn = 0; nn < 4; ++nn)
#pragma unroll
        for (int j = 0; j < 4; ++j) {
            const size_t rowoff = ((size_t)nn * SL + qr + fq * 4 + j) * SL;
#pragma unroll
            for (int nf = 0; nf < 4; ++nf)
                avg[rowoff + k0 + nf * 16 + fr] = acc[nn][nf][j];
        }
}

// ------------------- launcher -------------------
extern "C" void kernel_launch(void* const* d_in, const int* in_sizes, int n_in,
                              void* d_out, int out_size, void* d_ws, size_t ws_size,
                              hipStream_t stream)
{
    (void)in_sizes; (void)n_in; (void)out_size; (void)ws_size;
    const float* query = (const float*)d_in[0];
    const float* bias  = (const float*)d_in[1];
    const int* mask = (const int*)d_in[2];
    const float* Wq = (const float*)d_in[3];
    const float* bq = (const float*)d_in[4];
    const float* Wk = (const float*)d_in[5];
    const float* bk = (const float*)d_in[6];
    const float* Wv = (const float*)d_in[7];
    const float* bv = (const float*)d_in[8];
    const float* Wo = (const float*)d_in[9];
    const float* bo = (const float*)d_in[10];
    float* out0 = (float*)d_out;                      // [N,L,E]
    float* out1 = out0 + (size_t)MR * ED;             // [N,L,L]

    char* p = (char*)d_ws;
    auto carve = [&](size_t bytes) {
        char* r = p;
        p += (bytes + 255) & ~(size_t)255;
        return r;
    };
    const size_t QKVB = (size_t)NB * NH * SL * HD * 2;   // 16.78 MB
    bf16* xh = (bf16*)carve((size_t)MR * ED * 2);
    bf16* xl = (bf16*)carve((size_t)MR * ED * 2);
    bf16* wh = (bf16*)carve((size_t)4 * ED * ED * 2);
    bf16* wl = (bf16*)carve((size_t)4 * ED * ED * 2);
    bf16* qh = (bf16*)carve(QKVB);
    bf16* kh = (bf16*)carve(QKVB);
    bf16* vh = (bf16*)carve(QKVB);
    float* mrow = (float*)carve((size_t)NB * NH * SL * 4);
    float* srow = (float*)carve((size_t)NB * NH * SL * 4);
    float* mlg  = (float*)carve((size_t)NB * NH * SL * 4);
    bf16* ch = (bf16*)carve((size_t)MR * ED * 2);
    bf16* cl = (bf16*)carve((size_t)MR * ED * 2);

    // 1. split inputs to hi/lo bf16
    {
        const int n4 = MR * ED / 4;
        k_split<<<(n4 + 255) / 256, 256, 0, stream>>>(query, xh, xl, n4);
        const int w4 = ED * ED / 4;
        const float* Ws4[4] = {Wq, Wk, Wv, Wo};
        for (int i = 0; i < 4; ++i)
            k_split<<<(w4 + 255) / 256, 256, 0, stream>>>(
                Ws4[i], wh + (size_t)i * ED * ED, wl + (size_t)i * ED * ED, w4);
    }
    // 2. QKV projections
    k_qkv_gemm<<<dim3(MR / 128, ED / 128, 3), 256, 0, stream>>>(
        xh, xl, wh, wl, bq, bk, bv, qh, kh, vh);
    // 3. flash attention + row stats + context (QBLK=128 -> 1024 blocks)
    k_flash<<<dim3(1024), 256, 0, stream>>>(
        qh, kh, vh, bias, mask, ch, cl, mrow, srow);
    // 3b. mlg = m + ln(16 s)
    {
        const int nst = NB * NH * SL;
        k_mlg<<<(nst + 255) / 256, 256, 0, stream>>>(mrow, srow, mlg, nst);
    }
    // 4. head-averaged attention weights (64x64 tiles)
    k_avg<<<dim3(SL / 64, SL / 64), 256, 0, stream>>>(
        qh, kh, bias, mask, mlg, out1);
    // 5. output projection
    k_out_gemm<<<dim3(MR / 128, ED / 128), 256, 0, stream>>>(
        ch, cl, wh + (size_t)3 * ED * ED, wl + (size_t)3 * ED * ED, bo, out0);
}

// Round 18
// 510.513 us; speedup vs baseline: 1.5404x; 1.1839x over previous
//
#include <hip/hip_runtime.h>
#include <stdint.h>

typedef __bf16 bf16;
typedef __bf16 bf16x4 __attribute__((ext_vector_type(4)));
typedef __bf16 bf16x8 __attribute__((ext_vector_type(8)));
typedef float f32x4 __attribute__((ext_vector_type(4)));

#define MFMA16(a, b, c) __builtin_amdgcn_mfma_f32_16x16x32_bf16((a), (b), (c), 0, 0, 0)

static constexpr int NB = 4;      // batch
static constexpr int NH = 16;     // heads
static constexpr int SL = 2048;   // seq len
static constexpr int HD = 64;     // head dim
static constexpr int ED = 1024;   // embed
static constexpr int MR = NB * SL; // 8192 rows

__device__ __forceinline__ void gl_lds16(const void* g, void* l) {
    __builtin_amdgcn_global_load_lds(
        (const __attribute__((address_space(1))) unsigned int*)g,
        (__attribute__((address_space(3))) unsigned int*)l, 16, 0, 0);
}

// ------------------- f32 -> bf16 hi/lo split -------------------
__global__ void k_split(const float* __restrict__ src, bf16* __restrict__ hi,
                        bf16* __restrict__ lo, int n4) {
    int i = blockIdx.x * blockDim.x + threadIdx.x;
    if (i >= n4) return;
    const float4 v = ((const float4*)src)[i];
    float vv[4] = {v.x, v.y, v.z, v.w};
    bf16x4 hv, lv;
#pragma unroll
    for (int e = 0; e < 4; ++e) {
        bf16 h = (bf16)vv[e];
        hv[e] = h;
        lv[e] = (bf16)(vv[e] - (float)h);
    }
    ((bf16x4*)hi)[i] = hv;
    ((bf16x4*)lo)[i] = lv;
}

// ------------------- f32 -> bf16 plain cast -------------------
__global__ void k_cast(const float* __restrict__ src, bf16* __restrict__ dst, int n4) {
    int i = blockIdx.x * blockDim.x + threadIdx.x;
    if (i >= n4) return;
    const float4 v = ((const float4*)src)[i];
    bf16x4 hv = {(bf16)v.x, (bf16)v.y, (bf16)v.z, (bf16)v.w};
    ((bf16x4*)dst)[i] = hv;
}

// ------------------- mlg precompute: mlg = m + ln(16 s) -------------------
__global__ void k_mlg(const float* __restrict__ mrow, const float* __restrict__ srow,
                      float* __restrict__ mlg, int n) {
    int i = blockIdx.x * blockDim.x + threadIdx.x;
    if (i < n) mlg[i] = mrow[i] + __logf(16.0f * srow[i]);
}

// ------------------- QKV projection GEMM v2: hi-only (1 MFMA/pair) -------------------
__global__ __launch_bounds__(256) void k_qkv_gemm(
    const bf16* __restrict__ xh, const bf16* __restrict__ wh,
    const float* __restrict__ bq, const float* __restrict__ bk,
    const float* __restrict__ bv,
    bf16* __restrict__ qh, bf16* __restrict__ kh, bf16* __restrict__ vh)
{
    __shared__ __attribute__((aligned(16))) bf16 As[128 * 32];
    __shared__ __attribute__((aligned(16))) bf16 Bs[128 * 32];

    const int z  = blockIdx.z;           // 0=q,1=k,2=v
    const int m0 = blockIdx.x * 128;
    const int n0 = blockIdx.y * 128;
    const int tid = threadIdx.x, wave = tid >> 6, lane = tid & 63;
    const int wr = wave >> 1, wc = wave & 1;
    const int fr = lane & 15, fq = lane >> 4;
    const bf16* Wh = wh + (size_t)z * ED * ED;

    const f32x4 z4 = {0.f, 0.f, 0.f, 0.f};
    f32x4 acc[4][4];
#pragma unroll
    for (int i = 0; i < 4; ++i)
#pragma unroll
        for (int j = 0; j < 4; ++j) acc[i][j] = z4;

#pragma unroll 1
    for (int kk = 0; kk < ED; kk += 32) {
#pragma unroll
        for (int r = 0; r < 2; ++r) {
            const int chunk = r * 256 + tid;
            const int row = chunk >> 2, c8 = (chunk & 3) * 8;
            const size_t ax = (size_t)(m0 + row) * ED + kk + c8;
            const size_t bx = (size_t)(n0 + row) * ED + kk + c8;
            const int db = (r * 256 + wave * 64) * 8;   // wave-uniform LDS base
            gl_lds16(xh + ax, &As[db]);
            gl_lds16(Wh + bx, &Bs[db]);
        }
        __syncthreads();
        bf16x8 af[4], bfg[4];
#pragma unroll
        for (int i = 0; i < 4; ++i) {
            const int arow = wr * 64 + i * 16 + fr;
            af[i] = *(const bf16x8*)&As[arow * 32 + fq * 8];
            const int brow = wc * 64 + i * 16 + fr;
            bfg[i] = *(const bf16x8*)&Bs[brow * 32 + fq * 8];
        }
#pragma unroll
        for (int mi = 0; mi < 4; ++mi)
#pragma unroll
            for (int ni = 0; ni < 4; ++ni)
                acc[mi][ni] = MFMA16(af[mi], bfg[ni], acc[mi][ni]);
        __syncthreads();
    }

    const float* bias = (z == 0) ? bq : (z == 1) ? bk : bv;
#pragma unroll
    for (int mi = 0; mi < 4; ++mi) {
#pragma unroll
        for (int ni = 0; ni < 4; ++ni) {
            const int col = n0 + wc * 64 + ni * 16 + fr;
            const int hh = col >> 6, dd = col & 63;
#pragma unroll
            for (int j = 0; j < 4; ++j) {
                const int row = m0 + wr * 64 + mi * 16 + fq * 4 + j;
                float v = acc[mi][ni][j] + bias[col];
                const int nb = row >> 11, li = row & (SL - 1);
                const size_t off = (((size_t)nb * NH + hh) * SL + li) * HD + dd;
                if (z == 0) {
                    qh[off] = (bf16)(v * 0.125f);      // head_dim^-0.5
                } else if (z == 1) {
                    kh[off] = (bf16)v;
                } else {
                    vh[off] = (bf16)v;
                }
            }
        }
    }
}

// ------------------- output projection GEMM v2: A hi-only, W hi/lo (2 MFMA) -------------------
__global__ __launch_bounds__(256) void k_out_gemm(
    const bf16* __restrict__ ah,
    const bf16* __restrict__ wh, const bf16* __restrict__ wl,
    const float* __restrict__ bo, float* __restrict__ out)
{
    __shared__ __attribute__((aligned(16))) bf16 As[128 * 32];
    __shared__ __attribute__((aligned(16))) bf16 Bs[2][128 * 32];

    const int m0 = blockIdx.x * 128;
    const int n0 = blockIdx.y * 128;
    const int tid = threadIdx.x, wave = tid >> 6, lane = tid & 63;
    const int wr = wave >> 1, wc = wave & 1;
    const int fr = lane & 15, fq = lane >> 4;

    const f32x4 z4 = {0.f, 0.f, 0.f, 0.f};
    f32x4 acc[4][4];
#pragma unroll
    for (int i = 0; i < 4; ++i)
#pragma unroll
        for (int j = 0; j < 4; ++j) acc[i][j] = z4;

#pragma unroll 1
    for (int kk = 0; kk < ED; kk += 32) {
#pragma unroll
        for (int r = 0; r < 2; ++r) {
            const int chunk = r * 256 + tid;
            const int row = chunk >> 2, c8 = (chunk & 3) * 8;
            const size_t ax = (size_t)(m0 + row) * ED + kk + c8;
            const size_t bx = (size_t)(n0 + row) * ED + kk + c8;
            const int db = (r * 256 + wave * 64) * 8;
            gl_lds16(ah + ax, &As[db]);
            gl_lds16(wh + bx, &Bs[0][db]);
            gl_lds16(wl + bx, &Bs[1][db]);
        }
        __syncthreads();
        bf16x8 af[4], bfg[4][2];
#pragma unroll
        for (int i = 0; i < 4; ++i) {
            const int arow = wr * 64 + i * 16 + fr;
            af[i] = *(const bf16x8*)&As[arow * 32 + fq * 8];
            const int brow = wc * 64 + i * 16 + fr;
            bfg[i][0] = *(const bf16x8*)&Bs[0][brow * 32 + fq * 8];
            bfg[i][1] = *(const bf16x8*)&Bs[1][brow * 32 + fq * 8];
        }
#pragma unroll
        for (int mi = 0; mi < 4; ++mi)
#pragma unroll
            for (int ni = 0; ni < 4; ++ni) {
                acc[mi][ni] = MFMA16(af[mi], bfg[ni][0], acc[mi][ni]);
                acc[mi][ni] = MFMA16(af[mi], bfg[ni][1], acc[mi][ni]);
            }
        __syncthreads();
    }

#pragma unroll
    for (int mi = 0; mi < 4; ++mi)
#pragma unroll
        for (int ni = 0; ni < 4; ++ni) {
            const int col = n0 + wc * 64 + ni * 16 + fr;
#pragma unroll
            for (int j = 0; j < 4; ++j) {
                const int row = m0 + wr * 64 + mi * 16 + fq * 4 + j;
                out[(size_t)row * ED + col] = acc[mi][ni][j] + bo[col];
            }
        }
}

// ------------------- flash attention v10: v9 minus cl stream -------------------
__global__ __launch_bounds__(256) void k_flash(
    const bf16* __restrict__ qh, const bf16* __restrict__ kh,
    const bf16* __restrict__ vh,
    const float* __restrict__ bias, const int* __restrict__ mask,
    bf16* __restrict__ ch,
    float* __restrict__ mrow, float* __restrict__ srow)
{
    __shared__ __attribute__((aligned(16))) bf16 Ks[2][64 * 64];  // [key][d] swz, dbuf
    __shared__ __attribute__((aligned(16))) bf16 Vs[2][64 * 64];  // [d][key] swz, dbuf
    __shared__ __attribute__((aligned(16))) bf16 Ws[4][16 * 64];  // per-wave P, swz

    const int bid = blockIdx.x;
    const int xcd = bid & 7, local = bid >> 3;
    const int h = xcd * 2 + (local >> 6);
    const int rem = local & 63;
    const int qt = rem >> 2, n = rem & 3;

    const int tid = threadIdx.x, wave = tid >> 6, lane = tid & 63;
    const int fr = lane & 15, fq = lane >> 4;
    const int frx = fr & 7;
    const int q0 = qt * 128;
    const int qw = q0 + wave * 32;                  // wave's 32-row base
    const size_t hoff = ((size_t)n * NH + h) * SL * HD;
    const f32x4 z4 = {0.f, 0.f, 0.f, 0.f};

    bf16x8 qf0[2], qf1[2];
#pragma unroll
    for (int m = 0; m < 2; ++m) {
        const size_t qb = hoff + (size_t)(qw + m * 16 + fr) * HD + fq * 8;
        qf0[m] = *(const bf16x8*)(qh + qb);
        qf1[m] = *(const bf16x8*)(qh + qb + 32);
    }

    f32x4 o[2][4];
#pragma unroll
    for (int m = 0; m < 2; ++m)
#pragma unroll
        for (int f = 0; f < 4; ++f) o[m][f] = z4;
    float mj[2][4], sj[2][4];   // sj: LANE-LOCAL partial sums
#pragma unroll
    for (int m = 0; m < 2; ++m)
#pragma unroll
        for (int j = 0; j < 4; ++j) { mj[m][j] = -3e38f; sj[m][j] = 0.f; }

    const int* mkb = mask + n * SL;
    const float* bh = bias + (size_t)h * SL * SL;

    // ---- prologue ----
#pragma unroll
    for (int i = 0; i < 2; ++i) {
        const int li = i * 256 + tid;
        const int r = li >> 3, s = li & 7;
        gl_lds16(kh + hoff + (size_t)r * HD + (s ^ (r & 7)) * 8,
                 &Ks[0][(i * 256 + wave * 64) * 8]);
    }
    bf16x8 vr0 = *(const bf16x8*)(vh + hoff + (size_t)lane * HD + wave * 8);
    bf16x8 vr1 = *(const bf16x8*)(vh + hoff + (size_t)lane * HD + (wave + 4) * 8);
#pragma unroll
    for (int e = 0; e < 8; ++e) {
        const int d0 = wave * 8 + e, d1 = (wave + 4) * 8 + e;
        Vs[0][d0 * 64 + (((lane >> 3) ^ (d0 & 7)) << 3) + (lane & 7)] = vr0[e];
        Vs[0][d1 * 64 + (((lane >> 3) ^ (d1 & 7)) << 3) + (lane & 7)] = vr1[e];
    }
    vr0 = *(const bf16x8*)(vh + hoff + (size_t)(64 + lane) * HD + wave * 8);
    vr1 = *(const bf16x8*)(vh + hoff + (size_t)(64 + lane) * HD + (wave + 4) * 8);
    __syncthreads();   // drains K(0) DMA + Vs[0] writes

#pragma unroll 1
    for (int kt = 0; kt < 32; ++kt) {
        const int cur = kt & 1, nxt = cur ^ 1;
        const int kp1 = (kt < 31) ? kt + 1 : 31;
        const int kp2 = (kt < 30) ? kt + 2 : 31;

        // 0. mask bits for THIS tile (L1-hot; issued first, long cover)
        const int mw0 = mkb[kt * 64 + fr];
        const int mw1 = mkb[kt * 64 + 16 + fr];
        const int mw2 = mkb[kt * 64 + 32 + fr];
        const int mw3 = mkb[kt * 64 + 48 + fr];

        // 1. Vs[nxt] <- vr (V(kt+1))
#pragma unroll
        for (int e = 0; e < 8; ++e) {
            const int d0 = wave * 8 + e, d1 = (wave + 4) * 8 + e;
            Vs[nxt][d0 * 64 + (((lane >> 3) ^ (d0 & 7)) << 3) + (lane & 7)] = vr0[e];
            Vs[nxt][d1 * 64 + (((lane >> 3) ^ (d1 & 7)) << 3) + (lane & 7)] = vr1[e];
        }
        // 2. issue K(kt+1) -> Ks[nxt]
#pragma unroll
        for (int i = 0; i < 2; ++i) {
            const int li = i * 256 + tid;
            const int r = li >> 3, s = li & 7;
            gl_lds16(kh + hoff + (size_t)(kp1 * 64 + r) * HD + (s ^ (r & 7)) * 8,
                     &Ks[nxt][(i * 256 + wave * 64) * 8]);
        }
        // 3. V(kt+2) -> regs
        vr0 = *(const bf16x8*)(vh + hoff + (size_t)(kp2 * 64 + lane) * HD + wave * 8);
        vr1 = *(const bf16x8*)(vh + hoff + (size_t)(kp2 * 64 + lane) * HD + (wave + 4) * 8);
        const int mbits = (mw0 != 0 ? 1 : 0) | (mw1 != 0 ? 2 : 0)
                        | (mw2 != 0 ? 4 : 0) | (mw3 != 0 ? 8 : 0);

        // ---- compute: two independent 16-row chains ----
#pragma unroll
        for (int m = 0; m < 2; ++m) {
            float bfr[4][4];
#pragma unroll
            for (int nf = 0; nf < 4; ++nf)
#pragma unroll
                for (int j = 0; j < 4; ++j)
                    bfr[nf][j] = bh[(size_t)(qw + m * 16 + fq * 4 + j) * SL
                                    + kt * 64 + nf * 16 + fr];

            f32x4 sf[4];
            __builtin_amdgcn_s_setprio(1);
#pragma unroll
            for (int nf = 0; nf < 4; ++nf) {
                const bf16* kp = &Ks[cur][(nf * 16 + fr) * 64];
                const bf16x8 b0 = *(const bf16x8*)&kp[(fq ^ frx) * 8];
                const bf16x8 b1 = *(const bf16x8*)&kp[((fq + 4) ^ frx) * 8];
                f32x4 a = z4;
                a = MFMA16(qf0[m], b0, a);
                a = MFMA16(qf1[m], b1, a);
                sf[nf] = a;
            }
            __builtin_amdgcn_s_setprio(0);

            // bias + mask
#pragma unroll
            for (int nf = 0; nf < 4; ++nf) {
                const bool mk = (mbits >> nf) & 1;
#pragma unroll
                for (int j = 0; j < 4; ++j) {
                    float s = sf[nf][j] + bfr[nf][j];
                    sf[nf][j] = mk ? -1e30f : s;
                }
            }

            // defer-max online softmax (common path: no cross-lane ops)
            float tmax[4];
#pragma unroll
            for (int j = 0; j < 4; ++j)
                tmax[j] = fmaxf(fmaxf(sf[0][j], sf[1][j]), fmaxf(sf[2][j], sf[3][j]));
            bool need = false;
#pragma unroll
            for (int j = 0; j < 4; ++j)
                need = need || (tmax[j] > mj[m][j] + 8.0f);
            if (__any(need)) {
#pragma unroll
                for (int d = 1; d < 16; d <<= 1)
#pragma unroll
                    for (int j = 0; j < 4; ++j)
                        tmax[j] = fmaxf(tmax[j], __shfl_xor(tmax[j], d));
#pragma unroll
                for (int j = 0; j < 4; ++j) {
                    const float mn = fmaxf(mj[m][j], tmax[j]);
                    const float scale = __expf(mj[m][j] - mn);
                    mj[m][j] = mn;
                    sj[m][j] *= scale;
#pragma unroll
                    for (int f = 0; f < 4; ++f) o[m][f][j] *= scale;
                }
            }
#pragma unroll
            for (int nf = 0; nf < 4; ++nf)
#pragma unroll
                for (int j = 0; j < 4; ++j) {
                    const float w = __expf(sf[nf][j] - mj[m][j]);
                    sf[nf][j] = w;
                    sj[m][j] += w;
                }

            // P -> per-wave swizzled LDS tile (wave-local; reused across m)
#pragma unroll
            for (int nf = 0; nf < 4; ++nf)
#pragma unroll
                for (int j = 0; j < 4; ++j) {
                    const int row = fq * 4 + j, col = nf * 16 + fr;
                    Ws[wave][row * 64 + (((col >> 3) ^ (row & 7)) << 3) + (fr & 7)] =
                        (bf16)sf[nf][j];
                }
            const bf16* wp = &Ws[wave][fr * 64];
            const bf16x8 wa0 = *(const bf16x8*)&wp[(fq ^ frx) * 8];
            const bf16x8 wa1 = *(const bf16x8*)&wp[((fq + 4) ^ frx) * 8];
            __builtin_amdgcn_s_setprio(1);
#pragma unroll
            for (int f = 0; f < 4; ++f) {
                const bf16* vp = &Vs[cur][(f * 16 + fr) * 64];
                const bf16x8 vb0 = *(const bf16x8*)&vp[(fq ^ frx) * 8];
                const bf16x8 vb1 = *(const bf16x8*)&vp[((fq + 4) ^ frx) * 8];
                o[m][f] = MFMA16(wa0, vb0, o[m][f]);
                o[m][f] = MFMA16(wa1, vb1, o[m][f]);
            }
            __builtin_amdgcn_s_setprio(0);
        }

        __syncthreads();   // drains K(kt+1) DMA; fences Ks/Vs buffer swap
    }

    // epilogue: reduce lane-local sj across the 16-lane row group (once)
#pragma unroll
    for (int m = 0; m < 2; ++m)
#pragma unroll
        for (int d = 1; d < 16; d <<= 1)
#pragma unroll
            for (int j = 0; j < 4; ++j)
                sj[m][j] += __shfl_xor(sj[m][j], d);

    // context (hi only) + row stats, both m
#pragma unroll
    for (int m = 0; m < 2; ++m) {
#pragma unroll
        for (int j = 0; j < 4; ++j) {
            const float inv = 1.0f / sj[m][j];
            const int row = n * SL + qw + m * 16 + fq * 4 + j;
#pragma unroll
            for (int f = 0; f < 4; ++f) {
                const float v = o[m][f][j] * inv;
                const size_t off = (size_t)row * ED + h * HD + f * 16 + fr;
                ch[off] = (bf16)v;
            }
        }
        if (fr == 0) {
#pragma unroll
            for (int j = 0; j < 4; ++j) {
                const int r = qw + m * 16 + fq * 4 + j;
                mrow[((size_t)n * NH + h) * SL + r] = mj[m][j];
                srow[((size_t)n * NH + h) * SL + r] = sj[m][j];
            }
        }
    }
}

// ------------------- head-averaged weights v6: Q direct-to-reg, K-only LDS -------------------
__global__ __launch_bounds__(256) void k_avg(
    const bf16* __restrict__ qh, const bf16* __restrict__ kh,
    const float* __restrict__ bias, const int* __restrict__ mask,
    const float* __restrict__ mlg, float* __restrict__ avg)
{
    __shared__ __attribute__((aligned(16))) bf16 Ks2[2][64 * 64]; // 8KB x2

    const int qt = blockIdx.x, kt = blockIdx.y;
    const int tid = threadIdx.x, wave = tid >> 6, lane = tid & 63;
    const int fr = lane & 15, fq = lane >> 4;
    const int frx = fr & 7;
    const int q0 = qt * 64, k0 = kt * 64;
    const int qr = q0 + wave * 16;
    const f32x4 z4 = {0.f, 0.f, 0.f, 0.f};

    f32x4 acc[4][4];   // [nn][nf] -- all compile-time indices
#pragma unroll
    for (int nn = 0; nn < 4; ++nn)
#pragma unroll
        for (int nf = 0; nf < 4; ++nf) acc[nn][nf] = z4;

    // bitpack mask: bit (nn*4+nf)
    int mkbits = 0;
#pragma unroll
    for (int nn = 0; nn < 4; ++nn)
#pragma unroll
        for (int nf = 0; nf < 4; ++nf)
            mkbits |= (mask[nn * SL + k0 + nf * 16 + fr] != 0 ? 1 : 0) << (nn * 4 + nf);

    auto stageK = [&](int hh, int nn2, int b) {
        const bf16* kb = kh + (((size_t)nn2 * NH + hh) * SL + k0) * HD;
#pragma unroll
        for (int i = 0; i < 2; ++i) {
            const int li = i * 256 + tid;
            const int r = li >> 3, s = li & 7;
            gl_lds16(kb + (size_t)r * HD + (s ^ (r & 7)) * 8,
                     &Ks2[b][(i * 256 + wave * 64) * 8]);
        }
    };
    auto loadQ = [&](int hh, int nn2, bf16x8& a0, bf16x8& a1) {
        const bf16* qb = qh + ((((size_t)nn2 * NH + hh) * SL + qr + fr) * HD) + fq * 8;
        a0 = *(const bf16x8*)qb;
        a1 = *(const bf16x8*)(qb + 32);
    };
    auto loadMlg = [&](int hh, int nn2) -> f32x4 {
        return *(const f32x4*)(mlg + ((size_t)nn2 * NH + hh) * SL + qr + fq * 4);
    };

    // prologue: K(0,0) -> Ks2[0]; Q(0,0) + mlg(0,0) -> regs
    stageK(0, 0, 0);
    bf16x8 qcA, qcB;
    loadQ(0, 0, qcA, qcB);
    f32x4 mlgc = loadMlg(0, 0);
    __syncthreads();

#pragma unroll 1
    for (int h = 0; h < NH; ++h) {
        // bias tile rows for this h (consumed over 4 nn steps)
        float bfr[4][4];
#pragma unroll
        for (int nf = 0; nf < 4; ++nf)
#pragma unroll
            for (int j = 0; j < 4; ++j)
                bfr[nf][j] = bias[((size_t)h * SL + qr + fq * 4 + j) * SL + k0 + nf * 16 + fr];

#pragma unroll
        for (int nn = 0; nn < 4; ++nn) {
            const int ih = h * 4 + nn;           // unrolled: ih&1 is compile-time
            const int buf = ih & 1;

            // prefetch next step: K -> LDS[buf^1], Q + mlg -> regs
            bf16x8 qnA, qnB;
            f32x4 mlgn = mlgc;
            if (ih < 63) {
                const int jh = (ih + 1) >> 2, jnn = (ih + 1) & 3;
                stageK(jh, jnn, buf ^ 1);
                loadQ(jh, jnn, qnA, qnB);
                mlgn = loadMlg(jh, jnn);
            } else {
                qnA = qcA; qnB = qcB;
            }

            // compute on current (qcA/qcB, Ks2[buf], mlgc)
#pragma unroll
            for (int nf = 0; nf < 4; ++nf) {
                const bf16* kp = &Ks2[buf][(nf * 16 + fr) * 64];
                const bf16x8 b0 = *(const bf16x8*)&kp[(fq ^ frx) * 8];
                const bf16x8 b1 = *(const bf16x8*)&kp[((fq + 4) ^ frx) * 8];
                f32x4 a = z4;
                a = MFMA16(qcA, b0, a);
                a = MFMA16(qcB, b1, a);
                const bool mk = (mkbits >> (nn * 4 + nf)) & 1;
#pragma unroll
                for (int j = 0; j < 4; ++j) {
                    const float w = mk ? 0.f
                        : __expf(a[j] + bfr[nf][j] - mlgc[j]);
                    acc[nn][nf][j] += w;
                }
            }
            __syncthreads();    // drains next-K DMA; fences buffer swap
            qcA = qnA; qcB = qnB; mlgc = mlgn;
        }
    }

#pragma unroll
    for (int nn = 0; nn < 4; ++nn)
#pragma unroll
        for (int j = 0; j < 4; ++j) {
            const size_t rowoff = ((size_t)nn * SL + qr + fq * 4 + j) * SL;
#pragma unroll
            for (int nf = 0; nf < 4; ++nf)
                avg[rowoff + k0 + nf * 16 + fr] = acc[nn][nf][j];
        }
}

// ------------------- launcher -------------------
extern "C" void kernel_launch(void* const* d_in, const int* in_sizes, int n_in,
                              void* d_out, int out_size, void* d_ws, size_t ws_size,
                              hipStream_t stream)
{
    (void)in_sizes; (void)n_in; (void)out_size; (void)ws_size;
    const float* query = (const float*)d_in[0];
    const float* bias  = (const float*)d_in[1];
    const int* mask = (const int*)d_in[2];
    const float* Wq = (const float*)d_in[3];
    const float* bq = (const float*)d_in[4];
    const float* Wk = (const float*)d_in[5];
    const float* bk = (const float*)d_in[6];
    const float* Wv = (const float*)d_in[7];
    const float* bv = (const float*)d_in[8];
    const float* Wo = (const float*)d_in[9];
    const float* bo = (const float*)d_in[10];
    float* out0 = (float*)d_out;                      // [N,L,E]
    float* out1 = out0 + (size_t)MR * ED;             // [N,L,L]

    char* p = (char*)d_ws;
    auto carve = [&](size_t bytes) {
        char* r = p;
        p += (bytes + 255) & ~(size_t)255;
        return r;
    };
    const size_t QKVB = (size_t)NB * NH * SL * HD * 2;   // 16.78 MB
    bf16* xh = (bf16*)carve((size_t)MR * ED * 2);
    bf16* wqkv = (bf16*)carve((size_t)3 * ED * ED * 2);  // hi-only Wq,Wk,Wv
    bf16* woh = (bf16*)carve((size_t)ED * ED * 2);
    bf16* wol = (bf16*)carve((size_t)ED * ED * 2);
    bf16* qh = (bf16*)carve(QKVB);
    bf16* kh = (bf16*)carve(QKVB);
    bf16* vh = (bf16*)carve(QKVB);
    float* mrow = (float*)carve((size_t)NB * NH * SL * 4);
    float* srow = (float*)carve((size_t)NB * NH * SL * 4);
    float* mlg  = (float*)carve((size_t)NB * NH * SL * 4);
    bf16* ch = (bf16*)carve((size_t)MR * ED * 2);

    // 1. casts/splits
    {
        const int n4 = MR * ED / 4;
        k_cast<<<(n4 + 255) / 256, 256, 0, stream>>>(query, xh, n4);
        const int w4 = ED * ED / 4;
        const float* Ws3[3] = {Wq, Wk, Wv};
        for (int i = 0; i < 3; ++i)
            k_cast<<<(w4 + 255) / 256, 256, 0, stream>>>(
                Ws3[i], wqkv + (size_t)i * ED * ED, w4);
        k_split<<<(w4 + 255) / 256, 256, 0, stream>>>(Wo, woh, wol, w4);
    }
    // 2. QKV projections (hi-only)
    k_qkv_gemm<<<dim3(MR / 128, ED / 128, 3), 256, 0, stream>>>(
        xh, wqkv, bq, bk, bv, qh, kh, vh);
    // 3. flash attention + row stats + context (QBLK=128 -> 1024 blocks)
    k_flash<<<dim3(1024), 256, 0, stream>>>(
        qh, kh, vh, bias, mask, ch, mrow, srow);
    // 3b. mlg = m + ln(16 s)
    {
        const int nst = NB * NH * SL;
        k_mlg<<<(nst + 255) / 256, 256, 0, stream>>>(mrow, srow, mlg, nst);
    }
    // 4. head-averaged attention weights (64x64 tiles)
    k_avg<<<dim3(SL / 64, SL / 64), 256, 0, stream>>>(
        qh, kh, bias, mask, mlg, out1);
    // 5. output projection (A hi, W hi/lo)
    k_out_gemm<<<dim3(MR / 128, ED / 128), 256, 0, stream>>>(
        ch, woh, wol, bo, out0);
}